// Round 4
// baseline (382.990 us; speedup 1.0000x reference)
//
#include <hip/hip_runtime.h>
#include <math.h>

#define DM    1024
#define NH    16
#define HD    64
#define SEQ   2048
#define BATCH 4
#define TOKENS (BATCH * SEQ)     // 8192

typedef _Float16 half2v __attribute__((ext_vector_type(2)));
typedef __fp16   fp16x2 __attribute__((ext_vector_type(2)));
typedef _Float16 half4  __attribute__((ext_vector_type(4)));
typedef _Float16 half8  __attribute__((ext_vector_type(8)));
typedef float    f32x4  __attribute__((ext_vector_type(4)));
typedef float    f32x16 __attribute__((ext_vector_type(16)));
typedef unsigned int u32x2 __attribute__((ext_vector_type(2)));
typedef unsigned int u32x4 __attribute__((ext_vector_type(4)));

typedef const __attribute__((address_space(1))) void* gas_p;
typedef __attribute__((address_space(3))) void*       las_p;

__device__ __forceinline__ void gload_lds16(const void* g, void* l) {
    __builtin_amdgcn_global_load_lds((gas_p)g, (las_p)l, 16, 0, 0);
}

__device__ __forceinline__ unsigned pack2u(float a, float b) {
    fp16x2 r = __builtin_amdgcn_cvt_pkrtz(a, b);
    return __builtin_bit_cast(unsigned, r);
}

#define MFMA16(a, b, c) __builtin_amdgcn_mfma_f32_16x16x32_f16((a), (b), (c), 0, 0, 0)
#define MFMA32(a, b, c) __builtin_amdgcn_mfma_f32_32x32x16_f16((a), (b), (c), 0, 0, 0)

// ---------------------------------------------------------------------------
// One fused fp32->fp16 convert over all 7 tensors (dst regions contiguous).
// ---------------------------------------------------------------------------
__global__ __launch_bounds__(256) void cvt_all(
    const float* __restrict__ q, const float* __restrict__ k,
    const float* __restrict__ v, const float* __restrict__ wq,
    const float* __restrict__ wk, const float* __restrict__ wv,
    const float* __restrict__ wo, _Float16* __restrict__ dst)
{
    const size_t TD = (size_t)TOKENS * DM, WD = (size_t)DM * DM;
    const size_t i = ((size_t)blockIdx.x * 256 + threadIdx.x) * 4;
    const float* s; size_t off;
    if      (i <     TD)          { s = q;  off = i; }
    else if (i < 2 * TD)          { s = k;  off = i - TD; }
    else if (i < 3 * TD)          { s = v;  off = i - 2 * TD; }
    else if (i < 3 * TD + WD)     { s = wq; off = i - 3 * TD; }
    else if (i < 3 * TD + 2 * WD) { s = wk; off = i - 3 * TD - WD; }
    else if (i < 3 * TD + 3 * WD) { s = wv; off = i - 3 * TD - 2 * WD; }
    else                          { s = wo; off = i - 3 * TD - 3 * WD; }
    const float4 x = *(const float4*)(s + off);
    half4 h = { (_Float16)x.x, (_Float16)x.y, (_Float16)x.z, (_Float16)x.w };
    *(half4*)(dst + i) = h;
}

// ---------------------------------------------------------------------------
// Fused QKV projection: grid (64, 8, 3); z selects A/W/bias/C and store mode.
// z 0,1: per-head [B,H,S,hd] fp16 (z0 scaled by log2(e)/8); z 2: [B,H,hd,S].
// ---------------------------------------------------------------------------
__global__ __launch_bounds__(256) void qkv_gemm(
    const _Float16* __restrict__ Abase, const _Float16* __restrict__ Wbase,
    const float* __restrict__ bq, const float* __restrict__ bk,
    const float* __restrict__ bv, _Float16* __restrict__ Cbase, float qscale)
{
    __shared__ __align__(16) _Float16 As[128 * 32];
    __shared__ __align__(16) _Float16 Ws[128 * 32];

    const int z = blockIdx.z;
    const size_t TD = (size_t)TOKENS * DM, WD = (size_t)DM * DM;
    const _Float16* A = Abase + (size_t)z * TD;
    const _Float16* W = Wbase + (size_t)z * WD;
    const float* bias = (z == 0) ? bq : (z == 1) ? bk : bv;
    _Float16* C = Cbase + (size_t)z * TD;
    const float scale = (z == 0) ? qscale : 1.0f;

    const int t = threadIdx.x;
    const int w = t >> 6, l = t & 63;
    const int tx = l & 15, quad = l >> 4;
    const int m0 = blockIdx.x * 128, n0 = blockIdx.y * 128;
    const int wm = (w & 1) * 64, wn = (w >> 1) * 64;
    const int srow = t >> 2, schk = t & 3;

    const _Float16* Ag = A + (size_t)m0 * DM;
    const _Float16* Wg = W + (size_t)n0 * DM;

    f32x4 acc[4][4] = {};

    for (int k0 = 0; k0 < DM; k0 += 32) {
        __syncthreads();
        #pragma unroll
        for (int i = 0; i < 2; ++i) {
            gload_lds16(Ag + (size_t)(i * 64 + srow) * DM + k0 + schk * 8,
                        As + (size_t)(i * 256 + (t & ~63)) * 8);
            gload_lds16(Wg + (size_t)(i * 64 + srow) * DM + k0 + schk * 8,
                        Ws + (size_t)(i * 256 + (t & ~63)) * 8);
        }
        __syncthreads();

        half8 af[4], bf[4];
        #pragma unroll
        for (int mt = 0; mt < 4; ++mt)
            af[mt] = *(const half8*)(As + (wm + mt * 16 + tx) * 32 + quad * 8);
        #pragma unroll
        for (int nt = 0; nt < 4; ++nt)
            bf[nt] = *(const half8*)(Ws + (wn + nt * 16 + tx) * 32 + quad * 8);
        #pragma unroll
        for (int mt = 0; mt < 4; ++mt)
            #pragma unroll
            for (int nt = 0; nt < 4; ++nt)
                acc[mt][nt] = MFMA16(af[mt], bf[nt], acc[mt][nt]);
    }

    float bsv[4];
    #pragma unroll
    for (int nt = 0; nt < 4; ++nt) bsv[nt] = bias[n0 + wn + nt * 16 + tx];

    #pragma unroll
    for (int mt = 0; mt < 4; ++mt) {
        #pragma unroll
        for (int nt = 0; nt < 4; ++nt) {
            const int n = n0 + wn + nt * 16 + tx;
            const int mr0 = m0 + wm + mt * 16 + quad * 4;
            const int h = n >> 6, d = n & 63;
            if (z < 2) {
                #pragma unroll
                for (int r = 0; r < 4; ++r) {
                    const int m = mr0 + r;
                    const int b = m >> 11, s = m & (SEQ - 1);
                    const float vv = (acc[mt][nt][r] + bsv[nt]) * scale;
                    C[(((size_t)b * NH + h) * SEQ + s) * HD + d] = (_Float16)vv;
                }
            } else {
                const int b = mr0 >> 11, s0 = mr0 & (SEQ - 1);
                half4 hv = { (_Float16)(acc[mt][nt][0] + bsv[nt]),
                             (_Float16)(acc[mt][nt][1] + bsv[nt]),
                             (_Float16)(acc[mt][nt][2] + bsv[nt]),
                             (_Float16)(acc[mt][nt][3] + bsv[nt]) };
                *(half4*)(C + (((size_t)b * NH + h) * HD + d) * SEQ + s0) = hv;
            }
        }
    }
}

// ---------------------------------------------------------------------------
// Output projection GEMM: C fp32 [m,n] = A[m,k] W[n,k] + bias.
// ---------------------------------------------------------------------------
__global__ __launch_bounds__(256) void out_gemm(
    const _Float16* __restrict__ A, const _Float16* __restrict__ W,
    const float* __restrict__ bias, float* __restrict__ C)
{
    __shared__ __align__(16) _Float16 As[128 * 32];
    __shared__ __align__(16) _Float16 Ws[128 * 32];

    const int t = threadIdx.x;
    const int w = t >> 6, l = t & 63;
    const int tx = l & 15, quad = l >> 4;
    const int m0 = blockIdx.x * 128, n0 = blockIdx.y * 128;
    const int wm = (w & 1) * 64, wn = (w >> 1) * 64;
    const int srow = t >> 2, schk = t & 3;

    const _Float16* Ag = A + (size_t)m0 * DM;
    const _Float16* Wg = W + (size_t)n0 * DM;

    f32x4 acc[4][4] = {};

    for (int k0 = 0; k0 < DM; k0 += 32) {
        __syncthreads();
        #pragma unroll
        for (int i = 0; i < 2; ++i) {
            gload_lds16(Ag + (size_t)(i * 64 + srow) * DM + k0 + schk * 8,
                        As + (size_t)(i * 256 + (t & ~63)) * 8);
            gload_lds16(Wg + (size_t)(i * 64 + srow) * DM + k0 + schk * 8,
                        Ws + (size_t)(i * 256 + (t & ~63)) * 8);
        }
        __syncthreads();

        half8 af[4], bf[4];
        #pragma unroll
        for (int mt = 0; mt < 4; ++mt)
            af[mt] = *(const half8*)(As + (wm + mt * 16 + tx) * 32 + quad * 8);
        #pragma unroll
        for (int nt = 0; nt < 4; ++nt)
            bf[nt] = *(const half8*)(Ws + (wn + nt * 16 + tx) * 32 + quad * 8);
        #pragma unroll
        for (int mt = 0; mt < 4; ++mt)
            #pragma unroll
            for (int nt = 0; nt < 4; ++nt)
                acc[mt][nt] = MFMA16(af[mt], bf[nt], acc[mt][nt]);
    }

    float bsv[4];
    #pragma unroll
    for (int nt = 0; nt < 4; ++nt) bsv[nt] = bias[n0 + wn + nt * 16 + tx];

    #pragma unroll
    for (int mt = 0; mt < 4; ++mt)
        #pragma unroll
        for (int nt = 0; nt < 4; ++nt) {
            const int n = n0 + wn + nt * 16 + tx;
            const int mr0 = m0 + wm + mt * 16 + quad * 4;
            #pragma unroll
            for (int r = 0; r < 4; ++r)
                C[(size_t)(mr0 + r) * DM + n] = acc[mt][nt][r] + bsv[nt];
        }
}

// ---------------------------------------------------------------------------
// Flash attention v6 — split-K within block for 4 waves/SIMD occupancy.
// grid 1024 (XCD-bijective decode unchanged), block 256 = 4 waves.
// Pair p = w>>1 owns key half p*1024..p*1024+1023; wave-in-pair wp = w&1 owns
// q rows wp*64..wp*64+63 (two 32-col MFMA B-tiles). Each pair has its own
// double-buffered K/V LDS stream (64 KB total) -> 2 blocks/CU = 16 waves/CU
// = 4 waves/SIMD (v4/v5 were grid-starved at 2/SIMD, latency-bound).
// Exp2-domain no-max softmax => partial O and l from the two key halves
// merge by simple addition in the Obuf epilogue (two-phase, barriered).
// Per wave per tile: 16 S-MFMA + 64 exp2 + 32 cvt_pk + 16 permlane +
// 16 PV-MFMA on 16 ds_read_b128; 16 tiles per wave.
// ---------------------------------------------------------------------------
__global__ __launch_bounds__(256, 4) void flash16(
    const _Float16* __restrict__ Q, const _Float16* __restrict__ K,
    const _Float16* __restrict__ Vt, _Float16* __restrict__ AO)
{
    // pool: KA[2][8KB] | KB[2][8KB] | VA[2][8KB] | VB[2][8KB] = 65536 B
    // epilogue aliases pool as float Obuf[128][68] (34816 B)
    __shared__ __align__(16) char pool[65536];
    __shared__ float lW[128];

    const int t = threadIdx.x, w = t >> 6, l = t & 63;
    const int lid = l & 31, hl = l >> 5;
    const int p = w >> 1, wp = w & 1;     // key-half pair, wave-in-pair

    // XCD-bijective block swizzle: all 16 q-tiles of one (b,h) on one XCD.
    const int bid = blockIdx.x;
    const int xcd = bid & 7, loc = bid >> 3;
    const int bh = xcd * 8 + (loc >> 4);
    const int q0 = (loc & 15) * 128;
    const int b = bh >> 4, h = bh & 15;

    const _Float16* Qg = Q + ((size_t)bh * SEQ + q0 + wp * 64) * HD;
    const _Float16* Kg = K + ((size_t)bh * SEQ + p * 1024) * HD;
    const _Float16* Vg = Vt + (size_t)bh * HD * SEQ + p * 1024;

    // staging source swizzle (per lane, constant across iters)
    const int srow = l >> 3;             // 0..7 row within 8-row instr group
    const int schk = (l & 7) ^ srow;     // swizzled 16B chunk within 128B row

    // per-pair LDS stream bases
    char* const Kst = pool + p * 16384;
    char* const Vst = pool + 32768 + p * 16384;

    // Q B-fragments, in registers whole kernel: B[k=d][n=q], k = hl*8+j
    half8 Qf[2][4];
    #pragma unroll
    for (int qq = 0; qq < 2; ++qq)
        #pragma unroll
        for (int ks = 0; ks < 4; ++ks)
            Qf[qq][ks] = *(const half8*)(Qg + (size_t)(qq * 32 + lid) * HD + ks * 16 + hl * 8);

    f32x16 Oa[2][2] = {};    // D[q][d]: d = dt*32+lid, q = qq*32+(g*8+hl*4+r)
    float l2[2] = {0.f, 0.f};  // per-lane partial denom for q = qq*32+lid
    const half2v one2 = { (_Float16)1.0f, (_Float16)1.0f };

    // ---- stage tile 0 into buffer 0 (each pair stages its own stream;
    //      wave wp issues row-groups j = wp, wp+2, wp+4, wp+6)
    {
        _Float16* KL = (_Float16*)Kst;
        _Float16* VL = (_Float16*)Vst;
        #pragma unroll
        for (int jj = 0; jj < 4; ++jj) {
            const int j = wp + jj * 2;
            const int row = 8 * j + srow;
            gload_lds16(Kg + (size_t)row * HD + schk * 8, KL + j * 512);
            gload_lds16(Vg + (size_t)row * SEQ + schk * 8, VL + j * 512);
        }
    }

    const int NIT = SEQ / 2 / 64;   // 16 tiles per wave
    for (int it = 0; it < NIT; ++it) {
        __syncthreads();   // vmcnt(0)+barrier: tile `it` staged, prev compute done

        // ---- issue next-tile staging into the other buffer (overlaps compute)
        if (it < NIT - 1) {
            const int kb = (it + 1) * 64;
            _Float16* KL = (_Float16*)(Kst + ((it + 1) & 1) * 8192);
            _Float16* VL = (_Float16*)(Vst + ((it + 1) & 1) * 8192);
            #pragma unroll
            for (int jj = 0; jj < 4; ++jj) {
                const int j = wp + jj * 2;
                const int row = 8 * j + srow;
                gload_lds16(Kg + (size_t)(kb + row) * HD + schk * 8, KL + j * 512);
                gload_lds16(Vg + (size_t)row * SEQ + kb + schk * 8, VL + j * 512);
            }
        }

        const _Float16* KL = (const _Float16*)(Kst + (it & 1) * 8192);
        const _Float16* VL = (const _Float16*)(Vst + (it & 1) * 8192);

        // ---- K A-fragments: A[m=key][k=d], key = kt*32+lid, d = ks*16+hl*8+j
        half8 kf[2][4];
        #pragma unroll
        for (int kt = 0; kt < 2; ++kt)
            #pragma unroll
            for (int ks = 0; ks < 4; ++ks)
                kf[kt][ks] = *(const half8*)(KL + (kt * 32 + lid) * 64 +
                                             (((ks * 2 + hl) ^ (lid & 7)) * 8));

        // ---- per q-tile: S^T, softmax, in-register transpose to PV A-frags
        half8 pa[2][4];   // A[m=q][k=key], key = kstep*16 + hl*8 + j
        #pragma unroll
        for (int qq = 0; qq < 2; ++qq) {
            // S^T = K.Q^T : D[key][q]
            f32x16 sacc[2];
            __builtin_amdgcn_s_setprio(1);
            #pragma unroll
            for (int kt = 0; kt < 2; ++kt) {
                f32x16 s = {};
                #pragma unroll
                for (int ks = 0; ks < 4; ++ks)
                    s = MFMA32(kf[kt][ks], Qf[qq][ks], s);
                sacc[kt] = s;
            }
            __builtin_amdgcn_s_setprio(0);

            // P = exp2(S); l += sum; pack pairs of consecutive keys to fp16
            // cf[kt][g][s]: keys kt*32 + 8g + 4*hl + {2s, 2s+1}, q = qq*32+lid
            unsigned cf[2][4][2];
            #pragma unroll
            for (int kt = 0; kt < 2; ++kt)
                #pragma unroll
                for (int g = 0; g < 4; ++g) {
                    const float p0 = __builtin_amdgcn_exp2f(sacc[kt][g * 4 + 0]);
                    const float p1 = __builtin_amdgcn_exp2f(sacc[kt][g * 4 + 1]);
                    const float p2 = __builtin_amdgcn_exp2f(sacc[kt][g * 4 + 2]);
                    const float p3 = __builtin_amdgcn_exp2f(sacc[kt][g * 4 + 3]);
                    const unsigned ca = pack2u(p0, p1);
                    const unsigned cb = pack2u(p2, p3);
                    l2[qq] = __builtin_amdgcn_fdot2(__builtin_bit_cast(half2v, ca), one2, l2[qq], false);
                    l2[qq] = __builtin_amdgcn_fdot2(__builtin_bit_cast(half2v, cb), one2, l2[qq], false);
                    cf[kt][g][0] = ca;
                    cf[kt][g][1] = cb;
                }

            // build PV A-frags: 2 permlane32_swap per 16-key step
            #pragma unroll
            for (int kstep = 0; kstep < 4; ++kstep) {
                const int kt = kstep >> 1, g0 = (kstep & 1) * 2;
                const u32x2 r0 = __builtin_amdgcn_permlane32_swap(
                    cf[kt][g0][0], cf[kt][g0 + 1][0], false, false);
                const u32x2 r1 = __builtin_amdgcn_permlane32_swap(
                    cf[kt][g0][1], cf[kt][g0 + 1][1], false, false);
                const u32x4 pw = { r0[0], r1[0], r0[1], r1[1] };
                pa[qq][kstep] = __builtin_bit_cast(half8, pw);
            }
        }

        // ---- V B-fragments: B[k=key][n=d], key = kstep*16+hl*8+j, d = dt*32+lid
        half8 vf[4][2];
        #pragma unroll
        for (int kstep = 0; kstep < 4; ++kstep)
            #pragma unroll
            for (int dt = 0; dt < 2; ++dt)
                vf[kstep][dt] = *(const half8*)(VL + (dt * 32 + lid) * 64 +
                                                (((kstep * 2 + hl) ^ (lid & 7)) * 8));

        // ---- PV: D[q][d] += P.V  (4 independent accumulators)
        __builtin_amdgcn_s_setprio(1);
        #pragma unroll
        for (int kstep = 0; kstep < 4; ++kstep)
            #pragma unroll
            for (int qq = 0; qq < 2; ++qq)
                #pragma unroll
                for (int dt = 0; dt < 2; ++dt)
                    Oa[qq][dt] = MFMA32(pa[qq][kstep], vf[kstep][dt], Oa[qq][dt]);
        __builtin_amdgcn_s_setprio(0);
    }

    // ---- deferred denominator: reduce over lane halves
    #pragma unroll
    for (int qq = 0; qq < 2; ++qq)
        l2[qq] += __shfl_xor(l2[qq], 32, 64);

    __syncthreads();   // all K/V LDS reads done -> safe to alias pool as Obuf

    // ---- two-phase merge of the key-half partials into Obuf [128][68] fp32
    float* Ob = (float*)pool;
    if (p == 0) {
        #pragma unroll
        for (int qq = 0; qq < 2; ++qq)
            #pragma unroll
            for (int dt = 0; dt < 2; ++dt)
                #pragma unroll
                for (int g = 0; g < 4; ++g)
                    #pragma unroll
                    for (int r = 0; r < 4; ++r)
                        Ob[(wp * 64 + qq * 32 + g * 8 + hl * 4 + r) * 68 + dt * 32 + lid] =
                            Oa[qq][dt][g * 4 + r];
        if (l < 32) {
            lW[wp * 64 + l] = l2[0];
            lW[wp * 64 + 32 + l] = l2[1];
        }
    }
    __syncthreads();
    if (p == 1) {
        #pragma unroll
        for (int qq = 0; qq < 2; ++qq)
            #pragma unroll
            for (int dt = 0; dt < 2; ++dt)
                #pragma unroll
                for (int g = 0; g < 4; ++g)
                    #pragma unroll
                    for (int r = 0; r < 4; ++r)
                        Ob[(wp * 64 + qq * 32 + g * 8 + hl * 4 + r) * 68 + dt * 32 + lid] +=
                            Oa[qq][dt][g * 4 + r];
        if (l < 32) {
            lW[wp * 64 + l] += l2[0];
            lW[wp * 64 + 32 + l] += l2[1];
        }
    }
    __syncthreads();

    // ---- normalize + store AO [token][1024] fp16 (16B stores)
    {
        const int row = t >> 1, cb = (t & 1) * 32;
        const float inv = 1.0f / lW[row];
        _Float16* dst = AO + ((size_t)b * SEQ + q0 + row) * DM + h * HD + cb;
        #pragma unroll
        for (int j = 0; j < 32; j += 8) {
            const f32x4 o0 = *(const f32x4*)(Ob + row * 68 + cb + j);
            const f32x4 o1 = *(const f32x4*)(Ob + row * 68 + cb + j + 4);
            half8 hv = { (_Float16)(o0[0] * inv), (_Float16)(o0[1] * inv),
                         (_Float16)(o0[2] * inv), (_Float16)(o0[3] * inv),
                         (_Float16)(o1[0] * inv), (_Float16)(o1[1] * inv),
                         (_Float16)(o1[2] * inv), (_Float16)(o1[3] * inv) };
            *(half8*)(dst + j) = hv;
        }
    }
}

// ---------------------------------------------------------------------------
extern "C" void kernel_launch(void* const* d_in, const int* in_sizes, int n_in,
                              void* d_out, int out_size, void* d_ws, size_t ws_size,
                              hipStream_t stream)
{
    const float* q  = (const float*)d_in[0];
    const float* k  = (const float*)d_in[1];
    const float* v  = (const float*)d_in[2];
    const float* Wq = (const float*)d_in[3];
    const float* bq = (const float*)d_in[4];
    const float* Wk = (const float*)d_in[5];
    const float* bk = (const float*)d_in[6];
    const float* Wv = (const float*)d_in[7];
    const float* bv = (const float*)d_in[8];
    const float* Wo = (const float*)d_in[9];
    const float* bo = (const float*)d_in[10];
    float* out = (float*)d_out;

    const size_t TD = (size_t)TOKENS * DM;     // 8.39M
    const size_t WD = (size_t)DM * DM;         // 1.05M
    _Float16* ws = (_Float16*)d_ws;
    _Float16* cvtbase = ws;                    // q16|k16|v16|wq16|wk16|wv16|wo16
    _Float16* q16  = ws;
    _Float16* wq16 = ws + 3 * TD;
    _Float16* wo16 = wq16 + 3 * WD;
    _Float16* Qw   = ws + 3 * TD + 4 * WD;     // Qw|Kw|Vtw contiguous
    _Float16* Kw   = Qw + TD;
    _Float16* Vtw  = Kw + TD;
    _Float16* AOw  = Vtw + TD;

    const int gC = (int)((3 * TD + 4 * WD) / 4 / 256);   // 28672
    cvt_all<<<gC, 256, 0, stream>>>(q, k, v, Wq, Wk, Wv, Wo, cvtbase);

    const float qscale = 0.18033688011112042f; // log2(e)/sqrt(64)
    qkv_gemm<<<dim3(TOKENS / 128, DM / 128, 3), 256, 0, stream>>>(
        q16, wq16, bq, bk, bv, Qw, qscale);

    flash16<<<dim3((SEQ / 128) * BATCH * NH), 256, 0, stream>>>(Qw, Kw, Vtw, AOw);

    out_gemm<<<dim3(TOKENS / 128, DM / 128, 1), 256, 0, stream>>>(AOw, wo16, bo, out);
}

// Round 6
// 381.624 us; speedup vs baseline: 1.0036x; 1.0036x over previous
//
#include <hip/hip_runtime.h>
#include <math.h>

#define DM    1024
#define NH    16
#define HD    64
#define SEQ   2048
#define BATCH 4
#define TOKENS (BATCH * SEQ)     // 8192

typedef _Float16 half2v __attribute__((ext_vector_type(2)));
typedef __fp16   fp16x2 __attribute__((ext_vector_type(2)));
typedef _Float16 half4  __attribute__((ext_vector_type(4)));
typedef _Float16 half8  __attribute__((ext_vector_type(8)));
typedef float    f32x4  __attribute__((ext_vector_type(4)));
typedef float    f32x16 __attribute__((ext_vector_type(16)));
typedef unsigned int u32x2 __attribute__((ext_vector_type(2)));
typedef unsigned int u32x4 __attribute__((ext_vector_type(4)));

typedef const __attribute__((address_space(1))) void* gas_p;
typedef __attribute__((address_space(3))) void*       las_p;

__device__ __forceinline__ void gload_lds16(const void* g, void* l) {
    __builtin_amdgcn_global_load_lds((gas_p)g, (las_p)l, 16, 0, 0);
}

__device__ __forceinline__ unsigned pack2u(float a, float b) {
    fp16x2 r = __builtin_amdgcn_cvt_pkrtz(a, b);
    return __builtin_bit_cast(unsigned, r);
}

#define MFMA16(a, b, c) __builtin_amdgcn_mfma_f32_16x16x32_f16((a), (b), (c), 0, 0, 0)
#define MFMA32(a, b, c) __builtin_amdgcn_mfma_f32_32x32x16_f16((a), (b), (c), 0, 0, 0)

// ---------------------------------------------------------------------------
// One fused fp32->fp16 convert over all 7 tensors (dst regions contiguous).
// ---------------------------------------------------------------------------
__global__ __launch_bounds__(256) void cvt_all(
    const float* __restrict__ q, const float* __restrict__ k,
    const float* __restrict__ v, const float* __restrict__ wq,
    const float* __restrict__ wk, const float* __restrict__ wv,
    const float* __restrict__ wo, _Float16* __restrict__ dst)
{
    const size_t TD = (size_t)TOKENS * DM, WD = (size_t)DM * DM;
    const size_t i = ((size_t)blockIdx.x * 256 + threadIdx.x) * 4;
    const float* s; size_t off;
    if      (i <     TD)          { s = q;  off = i; }
    else if (i < 2 * TD)          { s = k;  off = i - TD; }
    else if (i < 3 * TD)          { s = v;  off = i - 2 * TD; }
    else if (i < 3 * TD + WD)     { s = wq; off = i - 3 * TD; }
    else if (i < 3 * TD + 2 * WD) { s = wk; off = i - 3 * TD - WD; }
    else if (i < 3 * TD + 3 * WD) { s = wv; off = i - 3 * TD - 2 * WD; }
    else                          { s = wo; off = i - 3 * TD - 3 * WD; }
    const float4 x = *(const float4*)(s + off);
    half4 h = { (_Float16)x.x, (_Float16)x.y, (_Float16)x.z, (_Float16)x.w };
    *(half4*)(dst + i) = h;
}

// ---------------------------------------------------------------------------
// Fused QKV projection: grid (64, 8, 3); z selects A/W/bias/C and store mode.
// z 0,1: per-head [B,H,S,hd] fp16 (z0 scaled by log2(e)/8); z 2: [B,H,hd,S].
// ---------------------------------------------------------------------------
__global__ __launch_bounds__(256) void qkv_gemm(
    const _Float16* __restrict__ Abase, const _Float16* __restrict__ Wbase,
    const float* __restrict__ bq, const float* __restrict__ bk,
    const float* __restrict__ bv, _Float16* __restrict__ Cbase, float qscale)
{
    __shared__ __align__(16) _Float16 As[128 * 32];
    __shared__ __align__(16) _Float16 Ws[128 * 32];

    const int z = blockIdx.z;
    const size_t TD = (size_t)TOKENS * DM, WD = (size_t)DM * DM;
    const _Float16* A = Abase + (size_t)z * TD;
    const _Float16* W = Wbase + (size_t)z * WD;
    const float* bias = (z == 0) ? bq : (z == 1) ? bk : bv;
    _Float16* C = Cbase + (size_t)z * TD;
    const float scale = (z == 0) ? qscale : 1.0f;

    const int t = threadIdx.x;
    const int w = t >> 6, l = t & 63;
    const int tx = l & 15, quad = l >> 4;
    const int m0 = blockIdx.x * 128, n0 = blockIdx.y * 128;
    const int wm = (w & 1) * 64, wn = (w >> 1) * 64;
    const int srow = t >> 2, schk = t & 3;

    const _Float16* Ag = A + (size_t)m0 * DM;
    const _Float16* Wg = W + (size_t)n0 * DM;

    f32x4 acc[4][4] = {};

    for (int k0 = 0; k0 < DM; k0 += 32) {
        __syncthreads();
        #pragma unroll
        for (int i = 0; i < 2; ++i) {
            gload_lds16(Ag + (size_t)(i * 64 + srow) * DM + k0 + schk * 8,
                        As + (size_t)(i * 256 + (t & ~63)) * 8);
            gload_lds16(Wg + (size_t)(i * 64 + srow) * DM + k0 + schk * 8,
                        Ws + (size_t)(i * 256 + (t & ~63)) * 8);
        }
        __syncthreads();

        half8 af[4], bf[4];
        #pragma unroll
        for (int mt = 0; mt < 4; ++mt)
            af[mt] = *(const half8*)(As + (wm + mt * 16 + tx) * 32 + quad * 8);
        #pragma unroll
        for (int nt = 0; nt < 4; ++nt)
            bf[nt] = *(const half8*)(Ws + (wn + nt * 16 + tx) * 32 + quad * 8);
        #pragma unroll
        for (int mt = 0; mt < 4; ++mt)
            #pragma unroll
            for (int nt = 0; nt < 4; ++nt)
                acc[mt][nt] = MFMA16(af[mt], bf[nt], acc[mt][nt]);
    }

    float bsv[4];
    #pragma unroll
    for (int nt = 0; nt < 4; ++nt) bsv[nt] = bias[n0 + wn + nt * 16 + tx];

    #pragma unroll
    for (int mt = 0; mt < 4; ++mt) {
        #pragma unroll
        for (int nt = 0; nt < 4; ++nt) {
            const int n = n0 + wn + nt * 16 + tx;
            const int mr0 = m0 + wm + mt * 16 + quad * 4;
            const int h = n >> 6, d = n & 63;
            if (z < 2) {
                #pragma unroll
                for (int r = 0; r < 4; ++r) {
                    const int m = mr0 + r;
                    const int b = m >> 11, s = m & (SEQ - 1);
                    const float vv = (acc[mt][nt][r] + bsv[nt]) * scale;
                    C[(((size_t)b * NH + h) * SEQ + s) * HD + d] = (_Float16)vv;
                }
            } else {
                const int b = mr0 >> 11, s0 = mr0 & (SEQ - 1);
                half4 hv = { (_Float16)(acc[mt][nt][0] + bsv[nt]),
                             (_Float16)(acc[mt][nt][1] + bsv[nt]),
                             (_Float16)(acc[mt][nt][2] + bsv[nt]),
                             (_Float16)(acc[mt][nt][3] + bsv[nt]) };
                *(half4*)(C + (((size_t)b * NH + h) * HD + d) * SEQ + s0) = hv;
            }
        }
    }
}

// ---------------------------------------------------------------------------
// Output projection GEMM: C fp32 [m,n] = A[m,k] W[n,k] + bias.
// ---------------------------------------------------------------------------
__global__ __launch_bounds__(256) void out_gemm(
    const _Float16* __restrict__ A, const _Float16* __restrict__ W,
    const float* __restrict__ bias, float* __restrict__ C)
{
    __shared__ __align__(16) _Float16 As[128 * 32];
    __shared__ __align__(16) _Float16 Ws[128 * 32];

    const int t = threadIdx.x;
    const int w = t >> 6, l = t & 63;
    const int tx = l & 15, quad = l >> 4;
    const int m0 = blockIdx.x * 128, n0 = blockIdx.y * 128;
    const int wm = (w & 1) * 64, wn = (w >> 1) * 64;
    const int srow = t >> 2, schk = t & 3;

    const _Float16* Ag = A + (size_t)m0 * DM;
    const _Float16* Wg = W + (size_t)n0 * DM;

    f32x4 acc[4][4] = {};

    for (int k0 = 0; k0 < DM; k0 += 32) {
        __syncthreads();
        #pragma unroll
        for (int i = 0; i < 2; ++i) {
            gload_lds16(Ag + (size_t)(i * 64 + srow) * DM + k0 + schk * 8,
                        As + (size_t)(i * 256 + (t & ~63)) * 8);
            gload_lds16(Wg + (size_t)(i * 64 + srow) * DM + k0 + schk * 8,
                        Ws + (size_t)(i * 256 + (t & ~63)) * 8);
        }
        __syncthreads();

        half8 af[4], bf[4];
        #pragma unroll
        for (int mt = 0; mt < 4; ++mt)
            af[mt] = *(const half8*)(As + (wm + mt * 16 + tx) * 32 + quad * 8);
        #pragma unroll
        for (int nt = 0; nt < 4; ++nt)
            bf[nt] = *(const half8*)(Ws + (wn + nt * 16 + tx) * 32 + quad * 8);
        #pragma unroll
        for (int mt = 0; mt < 4; ++mt)
            #pragma unroll
            for (int nt = 0; nt < 4; ++nt)
                acc[mt][nt] = MFMA16(af[mt], bf[nt], acc[mt][nt]);
    }

    float bsv[4];
    #pragma unroll
    for (int nt = 0; nt < 4; ++nt) bsv[nt] = bias[n0 + wn + nt * 16 + tx];

    #pragma unroll
    for (int mt = 0; mt < 4; ++mt)
        #pragma unroll
        for (int nt = 0; nt < 4; ++nt) {
            const int n = n0 + wn + nt * 16 + tx;
            const int mr0 = m0 + wm + mt * 16 + quad * 4;
            #pragma unroll
            for (int r = 0; r < 4; ++r)
                C[(size_t)(mr0 + r) * DM + n] = acc[mt][nt][r] + bsv[nt];
        }
}

// ---------------------------------------------------------------------------
// Flash attention v7 — direct-from-L2 K/V, zero barriers, 1-wave blocks.
// K/V per (b,h) = 512 KB; XCD swizzle puts 8 (b,h) per XCD = 4 MB = L2 size,
// so K/V fragment loads hit L2. No LDS staging in the main loop -> no
// vmcnt(0)+barrier drain per tile (the v4-v6 bottleneck); waves are fully
// independent, vmcnt is wave-local, compiler pipelines next-tile loads under
// compute. grid 2048 x 64 threads; wave owns 64 q rows (two 32-col B-tiles).
// Per tile: 8 K-loads + 8 V-loads (16B/lane, L1 absorbs sub-line re-reads),
// 16 S-MFMA, 64 exp2, 32 cvt_pk, 16 permlane, 16 PV-MFMA.
// Epilogue: per-wave [64][69] fp32 LDS transpose (odd stride, conflict-free).
// ---------------------------------------------------------------------------
__global__ __launch_bounds__(64, 2) void flash16(
    const _Float16* __restrict__ Q, const _Float16* __restrict__ K,
    const _Float16* __restrict__ Vt, _Float16* __restrict__ AO)
{
    __shared__ __align__(16) float Ob[64 * 69];   // 17664 B
    __shared__ float lw[64];

    const int l = threadIdx.x;
    const int lid = l & 31, hl = l >> 5;

    // XCD-bijective decode: all 32 q-tiles of one (b,h) on one XCD.
    const int bid = blockIdx.x;
    const int xcd = bid & 7, loc = bid >> 3;       // loc 0..255
    const int bh = xcd * 8 + (loc >> 5);           // 8 bh per XCD
    const int q0 = (loc & 31) * 64;
    const int b = bh >> 4, h = bh & 15;

    const _Float16* Qg = Q + ((size_t)bh * SEQ + q0) * HD;
    const _Float16* Kg = K + (size_t)bh * SEQ * HD;
    const _Float16* Vg = Vt + (size_t)bh * HD * SEQ;

    // Q B-fragments, in registers whole kernel: B[k=d][n=q], k = hl*8+j
    half8 Qf[2][4];
    #pragma unroll
    for (int qq = 0; qq < 2; ++qq)
        #pragma unroll
        for (int ks = 0; ks < 4; ++ks)
            Qf[qq][ks] = *(const half8*)(Qg + (size_t)(qq * 32 + lid) * HD + ks * 16 + hl * 8);

    f32x16 Oa[2][2] = {};      // D[q][d]: d = dt*32+lid, q = qq*32+(g*8+hl*4+r)
    float l2[2] = {0.f, 0.f};  // per-lane partial denom for q = qq*32+lid
    const half2v one2 = { (_Float16)1.0f, (_Float16)1.0f };

    for (int it = 0; it < SEQ / 64; ++it) {
        const int kb = it * 64;

        // ---- K A-fragments direct from L2: A[m=key][k=d]
        // key = kt*32+lid, d = ks*16+hl*8+j
        half8 kf[2][4];
        #pragma unroll
        for (int kt = 0; kt < 2; ++kt)
            #pragma unroll
            for (int ks = 0; ks < 4; ++ks)
                kf[kt][ks] = *(const half8*)(Kg + (size_t)(kb + kt * 32 + lid) * HD +
                                             ks * 16 + hl * 8);

        // ---- V B-fragments direct from L2: B[k=key][n=d]
        // key = kstep*16+hl*8+j, d = dt*32+lid  (issued early; consumed in PV)
        half8 vf[4][2];
        #pragma unroll
        for (int kstep = 0; kstep < 4; ++kstep)
            #pragma unroll
            for (int dt = 0; dt < 2; ++dt)
                vf[kstep][dt] = *(const half8*)(Vg + (size_t)(dt * 32 + lid) * SEQ +
                                                kb + kstep * 16 + hl * 8);

        // ---- per q-tile: S^T, softmax, in-register transpose to PV A-frags
        half8 pa[2][4];   // A[m=q][k=key], key = kstep*16 + hl*8 + j
        #pragma unroll
        for (int qq = 0; qq < 2; ++qq) {
            // S^T = K.Q^T : D[key][q]
            f32x16 sacc[2];
            __builtin_amdgcn_s_setprio(1);
            #pragma unroll
            for (int kt = 0; kt < 2; ++kt) {
                f32x16 s = {};
                #pragma unroll
                for (int ks = 0; ks < 4; ++ks)
                    s = MFMA32(kf[kt][ks], Qf[qq][ks], s);
                sacc[kt] = s;
            }
            __builtin_amdgcn_s_setprio(0);

            // P = exp2(S); l += sum; pack pairs of consecutive keys to fp16
            // cf[kt][g][s]: keys kt*32 + 8g + 4*hl + {2s, 2s+1}, q = qq*32+lid
            unsigned cf[2][4][2];
            #pragma unroll
            for (int kt = 0; kt < 2; ++kt)
                #pragma unroll
                for (int g = 0; g < 4; ++g) {
                    const float p0 = __builtin_amdgcn_exp2f(sacc[kt][g * 4 + 0]);
                    const float p1 = __builtin_amdgcn_exp2f(sacc[kt][g * 4 + 1]);
                    const float p2 = __builtin_amdgcn_exp2f(sacc[kt][g * 4 + 2]);
                    const float p3 = __builtin_amdgcn_exp2f(sacc[kt][g * 4 + 3]);
                    const unsigned ca = pack2u(p0, p1);
                    const unsigned cb = pack2u(p2, p3);
                    l2[qq] = __builtin_amdgcn_fdot2(__builtin_bit_cast(half2v, ca), one2, l2[qq], false);
                    l2[qq] = __builtin_amdgcn_fdot2(__builtin_bit_cast(half2v, cb), one2, l2[qq], false);
                    cf[kt][g][0] = ca;
                    cf[kt][g][1] = cb;
                }

            // build PV A-frags: 2 permlane32_swap per 16-key step
            #pragma unroll
            for (int kstep = 0; kstep < 4; ++kstep) {
                const int kt = kstep >> 1, g0 = (kstep & 1) * 2;
                const u32x2 r0 = __builtin_amdgcn_permlane32_swap(
                    cf[kt][g0][0], cf[kt][g0 + 1][0], false, false);
                const u32x2 r1 = __builtin_amdgcn_permlane32_swap(
                    cf[kt][g0][1], cf[kt][g0 + 1][1], false, false);
                const u32x4 pw = { r0[0], r1[0], r0[1], r1[1] };
                pa[qq][kstep] = __builtin_bit_cast(half8, pw);
            }
        }

        // ---- PV: D[q][d] += P.V  (4 independent accumulators)
        __builtin_amdgcn_s_setprio(1);
        #pragma unroll
        for (int kstep = 0; kstep < 4; ++kstep)
            #pragma unroll
            for (int qq = 0; qq < 2; ++qq)
                #pragma unroll
                for (int dt = 0; dt < 2; ++dt)
                    Oa[qq][dt] = MFMA32(pa[qq][kstep], vf[kstep][dt], Oa[qq][dt]);
        __builtin_amdgcn_s_setprio(0);
    }

    // ---- denominators: reduce over lane halves, publish to LDS
    #pragma unroll
    for (int qq = 0; qq < 2; ++qq)
        l2[qq] += __shfl_xor(l2[qq], 32, 64);
    if (l < 32) {
        lw[l] = l2[0];
        lw[32 + l] = l2[1];
    }

    // ---- O (C-layout regs) -> Ob [64][69] fp32 (odd stride: conflict-free)
    #pragma unroll
    for (int qq = 0; qq < 2; ++qq)
        #pragma unroll
        for (int dt = 0; dt < 2; ++dt)
            #pragma unroll
            for (int g = 0; g < 4; ++g)
                #pragma unroll
                for (int r = 0; r < 4; ++r)
                    Ob[(qq * 32 + g * 8 + hl * 4 + r) * 69 + dt * 32 + lid] =
                        Oa[qq][dt][g * 4 + r];
    __syncthreads();   // single-wave block: cheap; orders LDS writes vs reads

    // ---- normalize + store AO [token][1024] fp16 (16B stores), row = l
    {
        const float inv = 1.0f / lw[l];
        _Float16* dst = AO + ((size_t)b * SEQ + q0 + l) * DM + h * HD;
        #pragma unroll
        for (int j = 0; j < 64; j += 8) {
            const f32x4 o0 = *(const f32x4*)(Ob + l * 69 + j);
            const f32x4 o1 = *(const f32x4*)(Ob + l * 69 + j + 4);
            half8 hv = { (_Float16)(o0[0] * inv), (_Float16)(o0[1] * inv),
                         (_Float16)(o0[2] * inv), (_Float16)(o0[3] * inv),
                         (_Float16)(o1[0] * inv), (_Float16)(o1[1] * inv),
                         (_Float16)(o1[2] * inv), (_Float16)(o1[3] * inv) };
            *(half8*)(dst + j) = hv;
        }
    }
}

// ---------------------------------------------------------------------------
extern "C" void kernel_launch(void* const* d_in, const int* in_sizes, int n_in,
                              void* d_out, int out_size, void* d_ws, size_t ws_size,
                              hipStream_t stream)
{
    const float* q  = (const float*)d_in[0];
    const float* k  = (const float*)d_in[1];
    const float* v  = (const float*)d_in[2];
    const float* Wq = (const float*)d_in[3];
    const float* bq = (const float*)d_in[4];
    const float* Wk = (const float*)d_in[5];
    const float* bk = (const float*)d_in[6];
    const float* Wv = (const float*)d_in[7];
    const float* bv = (const float*)d_in[8];
    const float* Wo = (const float*)d_in[9];
    const float* bo = (const float*)d_in[10];
    float* out = (float*)d_out;

    const size_t TD = (size_t)TOKENS * DM;     // 8.39M
    const size_t WD = (size_t)DM * DM;         // 1.05M
    _Float16* ws = (_Float16*)d_ws;
    _Float16* cvtbase = ws;                    // q16|k16|v16|wq16|wk16|wv16|wo16
    _Float16* q16  = ws;
    _Float16* wq16 = ws + 3 * TD;
    _Float16* wo16 = wq16 + 3 * WD;
    _Float16* Qw   = ws + 3 * TD + 4 * WD;     // Qw|Kw|Vtw contiguous
    _Float16* Kw   = Qw + TD;
    _Float16* Vtw  = Kw + TD;
    _Float16* AOw  = Vtw + TD;

    const int gC = (int)((3 * TD + 4 * WD) / 4 / 256);   // 28672
    cvt_all<<<gC, 256, 0, stream>>>(q, k, v, Wq, Wk, Wv, Wo, cvtbase);

    const float qscale = 0.18033688011112042f; // log2(e)/sqrt(64)
    qkv_gemm<<<dim3(TOKENS / 128, DM / 128, 3), 256, 0, stream>>>(
        q16, wq16, bq, bk, bv, Qw, qscale);

    flash16<<<dim3((SEQ / 64) * BATCH * NH), 64, 0, stream>>>(Qw, Kw, Vtw, AOw);

    out_gemm<<<dim3(TOKENS / 128, DM / 128, 1), 256, 0, stream>>>(AOw, wo16, bo, out);
}

// Round 7
// 369.812 us; speedup vs baseline: 1.0356x; 1.0319x over previous
//
#include <hip/hip_runtime.h>
#include <math.h>

#define DM    1024
#define NH    16
#define HD    64
#define SEQ   2048
#define BATCH 4
#define TOKENS (BATCH * SEQ)     // 8192

typedef _Float16 half2v __attribute__((ext_vector_type(2)));
typedef __fp16   fp16x2 __attribute__((ext_vector_type(2)));
typedef _Float16 half4  __attribute__((ext_vector_type(4)));
typedef _Float16 half8  __attribute__((ext_vector_type(8)));
typedef float    f32x4  __attribute__((ext_vector_type(4)));
typedef float    f32x16 __attribute__((ext_vector_type(16)));
typedef unsigned int u32x2 __attribute__((ext_vector_type(2)));
typedef unsigned int u32x4 __attribute__((ext_vector_type(4)));

typedef const __attribute__((address_space(1))) void* gas_p;
typedef __attribute__((address_space(3))) void*       las_p;

__device__ __forceinline__ void gload_lds16(const void* g, void* l) {
    __builtin_amdgcn_global_load_lds((gas_p)g, (las_p)l, 16, 0, 0);
}

__device__ __forceinline__ unsigned pack2u(float a, float b) {
    fp16x2 r = __builtin_amdgcn_cvt_pkrtz(a, b);
    return __builtin_bit_cast(unsigned, r);
}

#define MFMA16(a, b, c) __builtin_amdgcn_mfma_f32_16x16x32_f16((a), (b), (c), 0, 0, 0)
#define MFMA32(a, b, c) __builtin_amdgcn_mfma_f32_32x32x16_f16((a), (b), (c), 0, 0, 0)

// ---------------------------------------------------------------------------
// One fused fp32->fp16 convert over all 7 tensors (dst regions contiguous).
// ---------------------------------------------------------------------------
__global__ __launch_bounds__(256) void cvt_all(
    const float* __restrict__ q, const float* __restrict__ k,
    const float* __restrict__ v, const float* __restrict__ wq,
    const float* __restrict__ wk, const float* __restrict__ wv,
    const float* __restrict__ wo, _Float16* __restrict__ dst)
{
    const size_t TD = (size_t)TOKENS * DM, WD = (size_t)DM * DM;
    const size_t i = ((size_t)blockIdx.x * 256 + threadIdx.x) * 4;
    const float* s; size_t off;
    if      (i <     TD)          { s = q;  off = i; }
    else if (i < 2 * TD)          { s = k;  off = i - TD; }
    else if (i < 3 * TD)          { s = v;  off = i - 2 * TD; }
    else if (i < 3 * TD + WD)     { s = wq; off = i - 3 * TD; }
    else if (i < 3 * TD + 2 * WD) { s = wk; off = i - 3 * TD - WD; }
    else if (i < 3 * TD + 3 * WD) { s = wv; off = i - 3 * TD - 2 * WD; }
    else                          { s = wo; off = i - 3 * TD - 3 * WD; }
    const float4 x = *(const float4*)(s + off);
    half4 h = { (_Float16)x.x, (_Float16)x.y, (_Float16)x.z, (_Float16)x.w };
    *(half4*)(dst + i) = h;
}

// ---------------------------------------------------------------------------
// Fused QKV projection: grid (64, 8, 3); z selects A/W/bias/C and store mode.
// z 0,1: per-head [B,H,S,hd] fp16 (z0 scaled by log2(e)/8); z 2: [B,H,hd,S].
// ---------------------------------------------------------------------------
__global__ __launch_bounds__(256) void qkv_gemm(
    const _Float16* __restrict__ Abase, const _Float16* __restrict__ Wbase,
    const float* __restrict__ bq, const float* __restrict__ bk,
    const float* __restrict__ bv, _Float16* __restrict__ Cbase, float qscale)
{
    __shared__ __align__(16) _Float16 As[128 * 32];
    __shared__ __align__(16) _Float16 Ws[128 * 32];

    const int z = blockIdx.z;
    const size_t TD = (size_t)TOKENS * DM, WD = (size_t)DM * DM;
    const _Float16* A = Abase + (size_t)z * TD;
    const _Float16* W = Wbase + (size_t)z * WD;
    const float* bias = (z == 0) ? bq : (z == 1) ? bk : bv;
    _Float16* C = Cbase + (size_t)z * TD;
    const float scale = (z == 0) ? qscale : 1.0f;

    const int t = threadIdx.x;
    const int w = t >> 6, l = t & 63;
    const int tx = l & 15, quad = l >> 4;
    const int m0 = blockIdx.x * 128, n0 = blockIdx.y * 128;
    const int wm = (w & 1) * 64, wn = (w >> 1) * 64;
    const int srow = t >> 2, schk = t & 3;

    const _Float16* Ag = A + (size_t)m0 * DM;
    const _Float16* Wg = W + (size_t)n0 * DM;

    f32x4 acc[4][4] = {};

    for (int k0 = 0; k0 < DM; k0 += 32) {
        __syncthreads();
        #pragma unroll
        for (int i = 0; i < 2; ++i) {
            gload_lds16(Ag + (size_t)(i * 64 + srow) * DM + k0 + schk * 8,
                        As + (size_t)(i * 256 + (t & ~63)) * 8);
            gload_lds16(Wg + (size_t)(i * 64 + srow) * DM + k0 + schk * 8,
                        Ws + (size_t)(i * 256 + (t & ~63)) * 8);
        }
        __syncthreads();

        half8 af[4], bf[4];
        #pragma unroll
        for (int mt = 0; mt < 4; ++mt)
            af[mt] = *(const half8*)(As + (wm + mt * 16 + tx) * 32 + quad * 8);
        #pragma unroll
        for (int nt = 0; nt < 4; ++nt)
            bf[nt] = *(const half8*)(Ws + (wn + nt * 16 + tx) * 32 + quad * 8);
        #pragma unroll
        for (int mt = 0; mt < 4; ++mt)
            #pragma unroll
            for (int nt = 0; nt < 4; ++nt)
                acc[mt][nt] = MFMA16(af[mt], bf[nt], acc[mt][nt]);
    }

    float bsv[4];
    #pragma unroll
    for (int nt = 0; nt < 4; ++nt) bsv[nt] = bias[n0 + wn + nt * 16 + tx];

    #pragma unroll
    for (int mt = 0; mt < 4; ++mt) {
        #pragma unroll
        for (int nt = 0; nt < 4; ++nt) {
            const int n = n0 + wn + nt * 16 + tx;
            const int mr0 = m0 + wm + mt * 16 + quad * 4;
            const int h = n >> 6, d = n & 63;
            if (z < 2) {
                #pragma unroll
                for (int r = 0; r < 4; ++r) {
                    const int m = mr0 + r;
                    const int b = m >> 11, s = m & (SEQ - 1);
                    const float vv = (acc[mt][nt][r] + bsv[nt]) * scale;
                    C[(((size_t)b * NH + h) * SEQ + s) * HD + d] = (_Float16)vv;
                }
            } else {
                const int b = mr0 >> 11, s0 = mr0 & (SEQ - 1);
                half4 hv = { (_Float16)(acc[mt][nt][0] + bsv[nt]),
                             (_Float16)(acc[mt][nt][1] + bsv[nt]),
                             (_Float16)(acc[mt][nt][2] + bsv[nt]),
                             (_Float16)(acc[mt][nt][3] + bsv[nt]) };
                *(half4*)(C + (((size_t)b * NH + h) * HD + d) * SEQ + s0) = hv;
            }
        }
    }
}

// ---------------------------------------------------------------------------
// Output projection GEMM: C fp32 [m,n] = A[m,k] W[n,k] + bias.
// ---------------------------------------------------------------------------
__global__ __launch_bounds__(256) void out_gemm(
    const _Float16* __restrict__ A, const _Float16* __restrict__ W,
    const float* __restrict__ bias, float* __restrict__ C)
{
    __shared__ __align__(16) _Float16 As[128 * 32];
    __shared__ __align__(16) _Float16 Ws[128 * 32];

    const int t = threadIdx.x;
    const int w = t >> 6, l = t & 63;
    const int tx = l & 15, quad = l >> 4;
    const int m0 = blockIdx.x * 128, n0 = blockIdx.y * 128;
    const int wm = (w & 1) * 64, wn = (w >> 1) * 64;
    const int srow = t >> 2, schk = t & 3;

    const _Float16* Ag = A + (size_t)m0 * DM;
    const _Float16* Wg = W + (size_t)n0 * DM;

    f32x4 acc[4][4] = {};

    for (int k0 = 0; k0 < DM; k0 += 32) {
        __syncthreads();
        #pragma unroll
        for (int i = 0; i < 2; ++i) {
            gload_lds16(Ag + (size_t)(i * 64 + srow) * DM + k0 + schk * 8,
                        As + (size_t)(i * 256 + (t & ~63)) * 8);
            gload_lds16(Wg + (size_t)(i * 64 + srow) * DM + k0 + schk * 8,
                        Ws + (size_t)(i * 256 + (t & ~63)) * 8);
        }
        __syncthreads();

        half8 af[4], bf[4];
        #pragma unroll
        for (int mt = 0; mt < 4; ++mt)
            af[mt] = *(const half8*)(As + (wm + mt * 16 + tx) * 32 + quad * 8);
        #pragma unroll
        for (int nt = 0; nt < 4; ++nt)
            bf[nt] = *(const half8*)(Ws + (wn + nt * 16 + tx) * 32 + quad * 8);
        #pragma unroll
        for (int mt = 0; mt < 4; ++mt)
            #pragma unroll
            for (int nt = 0; nt < 4; ++nt)
                acc[mt][nt] = MFMA16(af[mt], bf[nt], acc[mt][nt]);
    }

    float bsv[4];
    #pragma unroll
    for (int nt = 0; nt < 4; ++nt) bsv[nt] = bias[n0 + wn + nt * 16 + tx];

    #pragma unroll
    for (int mt = 0; mt < 4; ++mt)
        #pragma unroll
        for (int nt = 0; nt < 4; ++nt) {
            const int n = n0 + wn + nt * 16 + tx;
            const int mr0 = m0 + wm + mt * 16 + quad * 4;
            #pragma unroll
            for (int r = 0; r < 4; ++r)
                C[(size_t)(mr0 + r) * DM + n] = acc[mt][nt][r] + bsv[nt];
        }
}

// ---------------------------------------------------------------------------
// Flash attention v8 — wave-private LDS tiles + counted vmcnt, zero barriers.
// 1-wave blocks (grid 2048); wave owns 64 q rows, stages its OWN 32-key K/V
// tile (4KB+4KB, double-buffered = 16KB; Ob epilogue aliases pool -> 17.7KB
// -> 8 blocks/CU = 8 waves/CU). Per iter: issue next tile's 8 global_load_lds,
// s_waitcnt vmcnt(8) (current tile landed, next tile stays in flight across
// the whole compute phase), compute. No s_barrier in the main loop — the
// v4-v6 per-tile all-wave vmcnt(0) drain is structurally gone; waves
// self-pace. K swizzle: chunk^(row&7) (128B rows); V swizzle: chunk^((row>>1)&3)
// (64B rows, uniform 4-way = 1.58x, minimum possible).
// Per tile: 8 gload_lds, 4+4 ds_read_b128, 8 S-MFMA + 8 PV-MFMA (32x32x16),
// 32 exp2, 16 cvt_pk, 8 permlane; 64 tiles.
// ---------------------------------------------------------------------------
__global__ __launch_bounds__(64, 2) void flash16(
    const _Float16* __restrict__ Q, const _Float16* __restrict__ K,
    const _Float16* __restrict__ Vt, _Float16* __restrict__ AO)
{
    // pool: Kst[2][4096] | Vst[2][4096] = 16384 B
    // epilogue aliases pool as float Ob[64][69] (17664 B)
    __shared__ __align__(16) char pool[17664];
    __shared__ float lw[64];

    const int l = threadIdx.x;
    const int lid = l & 31, hl = l >> 5;

    // XCD-bijective decode: all 32 q-tiles of one (b,h) on one XCD.
    const int bid = blockIdx.x;
    const int xcd = bid & 7, loc = bid >> 3;       // loc 0..255
    const int bh = xcd * 8 + (loc >> 5);           // 8 bh per XCD
    const int q0 = (loc & 31) * 64;
    const int b = bh >> 4, h = bh & 15;

    const _Float16* Qg = Q + ((size_t)bh * SEQ + q0) * HD;
    const _Float16* Kg = K + (size_t)bh * SEQ * HD;
    const _Float16* Vg = Vt + (size_t)bh * HD * SEQ;

    // staging source swizzles (per lane, constant across iters)
    const int srk = l >> 3;                    // K: row within 8-row group
    const int sck = (l & 7) ^ srk;             // K: 16B chunk within 128B row
    const int srv = l >> 2;                    // V: row within 16-row group
    const int scv = (l & 3) ^ ((srv >> 1) & 3); // V: 16B chunk within 64B row

    // Q B-fragments, in registers whole kernel: B[k=d][n=q], k = hl*8+j
    half8 Qf[2][4];
    #pragma unroll
    for (int qq = 0; qq < 2; ++qq)
        #pragma unroll
        for (int ks = 0; ks < 4; ++ks)
            Qf[qq][ks] = *(const half8*)(Qg + (size_t)(qq * 32 + lid) * HD + ks * 16 + hl * 8);

    f32x16 Oa[2][2] = {};      // D[q][d]: d = dt*32+lid, q = qq*32+(g*8+hl*4+r)
    float l2[2] = {0.f, 0.f};  // per-lane partial denom for q = qq*32+lid
    const half2v one2 = { (_Float16)1.0f, (_Float16)1.0f };

    // ---- prologue: stage tile 0 into buffer 0 (8 loads, this wave only)
    {
        _Float16* KL = (_Float16*)pool;
        _Float16* VL = (_Float16*)(pool + 8192);
        #pragma unroll
        for (int j = 0; j < 4; ++j) {
            gload_lds16(Kg + (size_t)(8 * j + srk) * HD + sck * 8, KL + j * 512);
            gload_lds16(Vg + (size_t)(16 * j + srv) * SEQ + scv * 8, VL + j * 512);
        }
    }

    const int NIT = SEQ / 32;   // 64 tiles of 32 keys
    #pragma unroll 2
    for (int it = 0; it < NIT; ++it) {
        // ---- issue next tile's staging, then counted wait: current tile's
        //      8 loads complete, next tile's 8 stay in flight under compute.
        if (it < NIT - 1) {
            const int kb = (it + 1) * 32;
            _Float16* KL = (_Float16*)(pool + ((it + 1) & 1) * 4096);
            _Float16* VL = (_Float16*)(pool + 8192 + ((it + 1) & 1) * 4096);
            #pragma unroll
            for (int j = 0; j < 4; ++j) {
                gload_lds16(Kg + (size_t)(kb + 8 * j + srk) * HD + sck * 8, KL + j * 512);
                gload_lds16(Vg + (size_t)(16 * j + srv) * SEQ + kb + scv * 8, VL + j * 512);
            }
            asm volatile("s_waitcnt vmcnt(8)" ::: "memory");
        } else {
            asm volatile("s_waitcnt vmcnt(0)" ::: "memory");
        }

        const _Float16* KL = (const _Float16*)(pool + (it & 1) * 4096);
        const _Float16* VL = (const _Float16*)(pool + 8192 + (it & 1) * 4096);

        // ---- K A-fragments: A[m=key=lid][k=d], d = ks*16+hl*8+j (swizzled)
        half8 kf[4];
        #pragma unroll
        for (int ks = 0; ks < 4; ++ks)
            kf[ks] = *(const half8*)(KL + lid * 64 + (((ks * 2 + hl) ^ (lid & 7)) * 8));

        // ---- per q-tile: S^T, softmax, in-register transpose to PV A-frags
        half8 pa[2][2];   // A[m=q][k=key], key = kstep*16 + hl*8 + j
        #pragma unroll
        for (int qq = 0; qq < 2; ++qq) {
            // S^T = K.Q^T : D[key][q], 32 keys = one 32x32 accumulator
            f32x16 s = {};
            __builtin_amdgcn_s_setprio(1);
            #pragma unroll
            for (int ks = 0; ks < 4; ++ks)
                s = MFMA32(kf[ks], Qf[qq][ks], s);
            __builtin_amdgcn_s_setprio(0);

            // P = exp2(S); l += sum; pack pairs of consecutive keys to fp16
            // cf[g][s]: keys 8g + 4*hl + {2s, 2s+1}, q = qq*32+lid
            unsigned cf[4][2];
            #pragma unroll
            for (int g = 0; g < 4; ++g) {
                const float p0 = __builtin_amdgcn_exp2f(s[g * 4 + 0]);
                const float p1 = __builtin_amdgcn_exp2f(s[g * 4 + 1]);
                const float p2 = __builtin_amdgcn_exp2f(s[g * 4 + 2]);
                const float p3 = __builtin_amdgcn_exp2f(s[g * 4 + 3]);
                const unsigned ca = pack2u(p0, p1);
                const unsigned cb = pack2u(p2, p3);
                l2[qq] = __builtin_amdgcn_fdot2(__builtin_bit_cast(half2v, ca), one2, l2[qq], false);
                l2[qq] = __builtin_amdgcn_fdot2(__builtin_bit_cast(half2v, cb), one2, l2[qq], false);
                cf[g][0] = ca;
                cf[g][1] = cb;
            }

            // build PV A-frags: 2 permlane32_swap per 16-key step
            #pragma unroll
            for (int kstep = 0; kstep < 2; ++kstep) {
                const int g0 = kstep * 2;
                const u32x2 r0 = __builtin_amdgcn_permlane32_swap(
                    cf[g0][0], cf[g0 + 1][0], false, false);
                const u32x2 r1 = __builtin_amdgcn_permlane32_swap(
                    cf[g0][1], cf[g0 + 1][1], false, false);
                const u32x4 pw = { r0[0], r1[0], r0[1], r1[1] };
                pa[qq][kstep] = __builtin_bit_cast(half8, pw);
            }
        }

        // ---- V B-fragments: B[k=key][n=d], key = kstep*16+hl*8+j, d = dt*32+lid
        half8 vf[2][2];
        #pragma unroll
        for (int kstep = 0; kstep < 2; ++kstep)
            #pragma unroll
            for (int dt = 0; dt < 2; ++dt)
                vf[kstep][dt] = *(const half8*)(VL + (dt * 32 + lid) * 32 +
                                                (((kstep * 2 + hl) ^ ((lid >> 1) & 3)) * 8));

        // ---- PV: D[q][d] += P.V  (4 independent accumulators)
        __builtin_amdgcn_s_setprio(1);
        #pragma unroll
        for (int kstep = 0; kstep < 2; ++kstep)
            #pragma unroll
            for (int qq = 0; qq < 2; ++qq)
                #pragma unroll
                for (int dt = 0; dt < 2; ++dt)
                    Oa[qq][dt] = MFMA32(pa[qq][kstep], vf[kstep][dt], Oa[qq][dt]);
        __builtin_amdgcn_s_setprio(0);
    }

    // ---- denominators: reduce over lane halves, publish to LDS
    #pragma unroll
    for (int qq = 0; qq < 2; ++qq)
        l2[qq] += __shfl_xor(l2[qq], 32, 64);
    if (l < 32) {
        lw[l] = l2[0];
        lw[32 + l] = l2[1];
    }

    // ---- O (C-layout regs) -> Ob [64][69] fp32 (odd stride: conflict-free)
    float* Ob = (float*)pool;
    #pragma unroll
    for (int qq = 0; qq < 2; ++qq)
        #pragma unroll
        for (int dt = 0; dt < 2; ++dt)
            #pragma unroll
            for (int g = 0; g < 4; ++g)
                #pragma unroll
                for (int r = 0; r < 4; ++r)
                    Ob[(qq * 32 + g * 8 + hl * 4 + r) * 69 + dt * 32 + lid] =
                        Oa[qq][dt][g * 4 + r];
    __syncthreads();   // single-wave block: cheap; orders LDS writes vs reads

    // ---- normalize + store AO [token][1024] fp16 (16B stores), row = l
    {
        const float inv = 1.0f / lw[l];
        _Float16* dst = AO + ((size_t)b * SEQ + q0 + l) * DM + h * HD;
        #pragma unroll
        for (int j = 0; j < 64; j += 8) {
            const f32x4 o0 = *(const f32x4*)(Ob + l * 69 + j);
            const f32x4 o1 = *(const f32x4*)(Ob + l * 69 + j + 4);
            half8 hv = { (_Float16)(o0[0] * inv), (_Float16)(o0[1] * inv),
                         (_Float16)(o0[2] * inv), (_Float16)(o0[3] * inv),
                         (_Float16)(o1[0] * inv), (_Float16)(o1[1] * inv),
                         (_Float16)(o1[2] * inv), (_Float16)(o1[3] * inv) };
            *(half8*)(dst + j) = hv;
        }
    }
}

// ---------------------------------------------------------------------------
extern "C" void kernel_launch(void* const* d_in, const int* in_sizes, int n_in,
                              void* d_out, int out_size, void* d_ws, size_t ws_size,
                              hipStream_t stream)
{
    const float* q  = (const float*)d_in[0];
    const float* k  = (const float*)d_in[1];
    const float* v  = (const float*)d_in[2];
    const float* Wq = (const float*)d_in[3];
    const float* bq = (const float*)d_in[4];
    const float* Wk = (const float*)d_in[5];
    const float* bk = (const float*)d_in[6];
    const float* Wv = (const float*)d_in[7];
    const float* bv = (const float*)d_in[8];
    const float* Wo = (const float*)d_in[9];
    const float* bo = (const float*)d_in[10];
    float* out = (float*)d_out;

    const size_t TD = (size_t)TOKENS * DM;     // 8.39M
    const size_t WD = (size_t)DM * DM;         // 1.05M
    _Float16* ws = (_Float16*)d_ws;
    _Float16* cvtbase = ws;                    // q16|k16|v16|wq16|wk16|wv16|wo16
    _Float16* q16  = ws;
    _Float16* wq16 = ws + 3 * TD;
    _Float16* wo16 = wq16 + 3 * WD;
    _Float16* Qw   = ws + 3 * TD + 4 * WD;     // Qw|Kw|Vtw contiguous
    _Float16* Kw   = Qw + TD;
    _Float16* Vtw  = Kw + TD;
    _Float16* AOw  = Vtw + TD;

    const int gC = (int)((3 * TD + 4 * WD) / 4 / 256);   // 28672
    cvt_all<<<gC, 256, 0, stream>>>(q, k, v, Wq, Wk, Wv, Wo, cvtbase);

    const float qscale = 0.18033688011112042f; // log2(e)/sqrt(64)
    qkv_gemm<<<dim3(TOKENS / 128, DM / 128, 3), 256, 0, stream>>>(
        q16, wq16, bq, bk, bv, Qw, qscale);

    flash16<<<dim3((SEQ / 64) * BATCH * NH), 64, 0, stream>>>(Qw, Kw, Vtw, AOw);

    out_gemm<<<dim3(TOKENS / 128, DM / 128, 1), 256, 0, stream>>>(AOw, wo16, bo, out);
}

// Round 8
// 348.245 us; speedup vs baseline: 1.0998x; 1.0619x over previous
//
#include <hip/hip_runtime.h>
#include <math.h>

#define DM    1024
#define NH    16
#define HD    64
#define SEQ   2048
#define BATCH 4
#define TOKENS (BATCH * SEQ)     // 8192

typedef _Float16 half2v __attribute__((ext_vector_type(2)));
typedef __fp16   fp16x2 __attribute__((ext_vector_type(2)));
typedef _Float16 half4  __attribute__((ext_vector_type(4)));
typedef _Float16 half8  __attribute__((ext_vector_type(8)));
typedef float    f32x4  __attribute__((ext_vector_type(4)));
typedef float    f32x16 __attribute__((ext_vector_type(16)));
typedef unsigned int u32x2 __attribute__((ext_vector_type(2)));
typedef unsigned int u32x4 __attribute__((ext_vector_type(4)));

typedef const __attribute__((address_space(1))) void* gas_p;
typedef __attribute__((address_space(3))) void*       las_p;

__device__ __forceinline__ void gload_lds16(const void* g, void* l) {
    __builtin_amdgcn_global_load_lds((gas_p)g, (las_p)l, 16, 0, 0);
}

__device__ __forceinline__ unsigned pack2u(float a, float b) {
    fp16x2 r = __builtin_amdgcn_cvt_pkrtz(a, b);
    return __builtin_bit_cast(unsigned, r);
}

#define MFMA16(a, b, c) __builtin_amdgcn_mfma_f32_16x16x32_f16((a), (b), (c), 0, 0, 0)
#define MFMA32(a, b, c) __builtin_amdgcn_mfma_f32_32x32x16_f16((a), (b), (c), 0, 0, 0)

// ---------------------------------------------------------------------------
// One fused fp32->fp16 convert over all 7 tensors (dst regions contiguous).
// ---------------------------------------------------------------------------
__global__ __launch_bounds__(256) void cvt_all(
    const float* __restrict__ q, const float* __restrict__ k,
    const float* __restrict__ v, const float* __restrict__ wq,
    const float* __restrict__ wk, const float* __restrict__ wv,
    const float* __restrict__ wo, _Float16* __restrict__ dst)
{
    const size_t TD = (size_t)TOKENS * DM, WD = (size_t)DM * DM;
    const size_t i = ((size_t)blockIdx.x * 256 + threadIdx.x) * 4;
    const float* s; size_t off;
    if      (i <     TD)          { s = q;  off = i; }
    else if (i < 2 * TD)          { s = k;  off = i - TD; }
    else if (i < 3 * TD)          { s = v;  off = i - 2 * TD; }
    else if (i < 3 * TD + WD)     { s = wq; off = i - 3 * TD; }
    else if (i < 3 * TD + 2 * WD) { s = wk; off = i - 3 * TD - WD; }
    else if (i < 3 * TD + 3 * WD) { s = wv; off = i - 3 * TD - 2 * WD; }
    else                          { s = wo; off = i - 3 * TD - 3 * WD; }
    const float4 x = *(const float4*)(s + off);
    half4 h = { (_Float16)x.x, (_Float16)x.y, (_Float16)x.z, (_Float16)x.w };
    *(half4*)(dst + i) = h;
}

// ---------------------------------------------------------------------------
// Fused QKV projection: grid (64, 8, 3); z selects A/W/bias/C.
// All z store per-head [B,H,S,hd] fp16 (z0 scaled by log2(e)/8); z2 goes to
// the natural-V scratch (Cv) — the 4KB-stride transposed scatter is gone,
// V^T is produced by the separate vtr kernel.
// ---------------------------------------------------------------------------
__global__ __launch_bounds__(256) void qkv_gemm(
    const _Float16* __restrict__ Abase, const _Float16* __restrict__ Wbase,
    const float* __restrict__ bq, const float* __restrict__ bk,
    const float* __restrict__ bv, _Float16* __restrict__ Cbase,
    _Float16* __restrict__ Cv, float qscale)
{
    __shared__ __align__(16) _Float16 As[128 * 32];
    __shared__ __align__(16) _Float16 Ws[128 * 32];

    const int z = blockIdx.z;
    const size_t TD = (size_t)TOKENS * DM, WD = (size_t)DM * DM;
    const _Float16* A = Abase + (size_t)z * TD;
    const _Float16* W = Wbase + (size_t)z * WD;
    const float* bias = (z == 0) ? bq : (z == 1) ? bk : bv;
    _Float16* C = (z == 2) ? Cv : Cbase + (size_t)z * TD;
    const float scale = (z == 0) ? qscale : 1.0f;

    const int t = threadIdx.x;
    const int w = t >> 6, l = t & 63;
    const int tx = l & 15, quad = l >> 4;
    const int m0 = blockIdx.x * 128, n0 = blockIdx.y * 128;
    const int wm = (w & 1) * 64, wn = (w >> 1) * 64;
    const int srow = t >> 2, schk = t & 3;

    const _Float16* Ag = A + (size_t)m0 * DM;
    const _Float16* Wg = W + (size_t)n0 * DM;

    f32x4 acc[4][4] = {};

    for (int k0 = 0; k0 < DM; k0 += 32) {
        __syncthreads();
        #pragma unroll
        for (int i = 0; i < 2; ++i) {
            gload_lds16(Ag + (size_t)(i * 64 + srow) * DM + k0 + schk * 8,
                        As + (size_t)(i * 256 + (t & ~63)) * 8);
            gload_lds16(Wg + (size_t)(i * 64 + srow) * DM + k0 + schk * 8,
                        Ws + (size_t)(i * 256 + (t & ~63)) * 8);
        }
        __syncthreads();

        half8 af[4], bf[4];
        #pragma unroll
        for (int mt = 0; mt < 4; ++mt)
            af[mt] = *(const half8*)(As + (wm + mt * 16 + tx) * 32 + quad * 8);
        #pragma unroll
        for (int nt = 0; nt < 4; ++nt)
            bf[nt] = *(const half8*)(Ws + (wn + nt * 16 + tx) * 32 + quad * 8);
        #pragma unroll
        for (int mt = 0; mt < 4; ++mt)
            #pragma unroll
            for (int nt = 0; nt < 4; ++nt)
                acc[mt][nt] = MFMA16(af[mt], bf[nt], acc[mt][nt]);
    }

    float bsv[4];
    #pragma unroll
    for (int nt = 0; nt < 4; ++nt) bsv[nt] = bias[n0 + wn + nt * 16 + tx];

    #pragma unroll
    for (int mt = 0; mt < 4; ++mt) {
        #pragma unroll
        for (int nt = 0; nt < 4; ++nt) {
            const int n = n0 + wn + nt * 16 + tx;
            const int mr0 = m0 + wm + mt * 16 + quad * 4;
            const int h = n >> 6, d = n & 63;
            #pragma unroll
            for (int r = 0; r < 4; ++r) {
                const int m = mr0 + r;
                const int b = m >> 11, s = m & (SEQ - 1);
                const float vv = (acc[mt][nt][r] + bsv[nt]) * scale;
                C[(((size_t)b * NH + h) * SEQ + s) * HD + d] = (_Float16)vv;
            }
        }
    }
}

// ---------------------------------------------------------------------------
// V transpose: [b,h,s,hd] -> [b,h,hd,s] via padded LDS tile.
// grid (SEQ/64, B*NH), block 256. Reads full 64B-line chunks; writes full
// 128B d-rows (8 lanes x 16B per row, 8 rows per wave-inst).
// ---------------------------------------------------------------------------
__global__ __launch_bounds__(256) void vtr(
    const _Float16* __restrict__ Vn, _Float16* __restrict__ Vt)
{
    __shared__ _Float16 T[64 * 72];
    const int bh = blockIdx.y;
    const int s0 = blockIdx.x * 64;
    const int t = threadIdx.x;

    // read 64 s-rows x 64 d; thread reads two 16B chunks of its s-row
    {
        const int sr = t >> 2, c0 = t & 3;
        const _Float16* src = Vn + ((size_t)bh * SEQ + s0 + sr) * HD;
        #pragma unroll
        for (int j = 0; j < 2; ++j) {
            const int c = c0 + j * 4;
            *(half8*)&T[sr * 72 + c * 8] = *(const half8*)(src + c * 8);
        }
    }
    __syncthreads();

    // write 64 d-rows x 64 s; wave covers 8 d-rows x 8 chunks (full rows)
    {
        const int w = t >> 6, l = t & 63;
        #pragma unroll
        for (int pass = 0; pass < 2; ++pass) {
            const int dr = pass * 32 + w * 8 + (l >> 3);
            const int cc = l & 7;
            half8 o;
            #pragma unroll
            for (int jj = 0; jj < 8; ++jj)
                o[jj] = T[(cc * 8 + jj) * 72 + dr];
            *(half8*)(Vt + ((size_t)bh * HD + dr) * SEQ + s0 + cc * 8) = o;
        }
    }
}

// ---------------------------------------------------------------------------
// Output projection GEMM: C fp32 [m,n] = A[m,k] W[n,k] + bias.
// ---------------------------------------------------------------------------
__global__ __launch_bounds__(256) void out_gemm(
    const _Float16* __restrict__ A, const _Float16* __restrict__ W,
    const float* __restrict__ bias, float* __restrict__ C)
{
    __shared__ __align__(16) _Float16 As[128 * 32];
    __shared__ __align__(16) _Float16 Ws[128 * 32];

    const int t = threadIdx.x;
    const int w = t >> 6, l = t & 63;
    const int tx = l & 15, quad = l >> 4;
    const int m0 = blockIdx.x * 128, n0 = blockIdx.y * 128;
    const int wm = (w & 1) * 64, wn = (w >> 1) * 64;
    const int srow = t >> 2, schk = t & 3;

    const _Float16* Ag = A + (size_t)m0 * DM;
    const _Float16* Wg = W + (size_t)n0 * DM;

    f32x4 acc[4][4] = {};

    for (int k0 = 0; k0 < DM; k0 += 32) {
        __syncthreads();
        #pragma unroll
        for (int i = 0; i < 2; ++i) {
            gload_lds16(Ag + (size_t)(i * 64 + srow) * DM + k0 + schk * 8,
                        As + (size_t)(i * 256 + (t & ~63)) * 8);
            gload_lds16(Wg + (size_t)(i * 64 + srow) * DM + k0 + schk * 8,
                        Ws + (size_t)(i * 256 + (t & ~63)) * 8);
        }
        __syncthreads();

        half8 af[4], bf[4];
        #pragma unroll
        for (int mt = 0; mt < 4; ++mt)
            af[mt] = *(const half8*)(As + (wm + mt * 16 + tx) * 32 + quad * 8);
        #pragma unroll
        for (int nt = 0; nt < 4; ++nt)
            bf[nt] = *(const half8*)(Ws + (wn + nt * 16 + tx) * 32 + quad * 8);
        #pragma unroll
        for (int mt = 0; mt < 4; ++mt)
            #pragma unroll
            for (int nt = 0; nt < 4; ++nt)
                acc[mt][nt] = MFMA16(af[mt], bf[nt], acc[mt][nt]);
    }

    float bsv[4];
    #pragma unroll
    for (int nt = 0; nt < 4; ++nt) bsv[nt] = bias[n0 + wn + nt * 16 + tx];

    #pragma unroll
    for (int mt = 0; mt < 4; ++mt)
        #pragma unroll
        for (int nt = 0; nt < 4; ++nt) {
            const int n = n0 + wn + nt * 16 + tx;
            const int mr0 = m0 + wm + mt * 16 + quad * 4;
            #pragma unroll
            for (int r = 0; r < 4; ++r)
                C[(size_t)(mr0 + r) * DM + n] = acc[mt][nt][r] + bsv[nt];
        }
}

// ---------------------------------------------------------------------------
// Flash attention v4 (best measured: 95.2 us) — 32x32 MFMA + in-register
// softmax. grid 1024 (XCD-bijective decode), block 256 = 4 waves; wave w
// owns q rows w*32..w*32+31 (split-Q, l deferred). K-tile 64 keys,
// double-buffered LDS via global_load_lds with XOR-swizzled global source;
// fragment reads apply the same involution -> conflict-free b128.
// S^T = mfma_32x32x16(K, Q); P = exp2(S) packed via cvt_pkrtz; PV A-frags
// built in-register with permlane32_swap — no P LDS round trip.
// ---------------------------------------------------------------------------
__global__ __launch_bounds__(256, 3) void flash16(
    const _Float16* __restrict__ Q, const _Float16* __restrict__ K,
    const _Float16* __restrict__ Vt, _Float16* __restrict__ AO)
{
    // pool: Kst[2][8KB] | Vst[2][8KB] = 32768 B
    // epilogue aliases pool as float Obuf[128][68] (34816 B)
    __shared__ __align__(16) char pool[34816];
    __shared__ float lW[128];

    const int t = threadIdx.x, w = t >> 6, l = t & 63;
    const int lid = l & 31, hl = l >> 5;

    // XCD-bijective block swizzle: all 16 q-tiles of one (b,h) on one XCD.
    const int bid = blockIdx.x;
    const int xcd = bid & 7, loc = bid >> 3;
    const int bh = xcd * 8 + (loc >> 4);
    const int q0 = (loc & 15) * 128;
    const int b = bh >> 4, h = bh & 15;

    const _Float16* Qg = Q + ((size_t)bh * SEQ + q0 + w * 32) * HD;
    const _Float16* Kg = K + (size_t)bh * SEQ * HD;
    const _Float16* Vg = Vt + (size_t)bh * HD * SEQ;

    // staging source swizzle (per lane, constant across iters)
    const int srow = l >> 3;             // 0..7 row within 8-row instr group
    const int schk = (l & 7) ^ srow;     // swizzled 16B chunk within 128B row

    // Q B-fragments, in registers whole kernel: B[k=d][n=q], k = hl*8+j
    half8 Qf[4];
    #pragma unroll
    for (int ks = 0; ks < 4; ++ks)
        Qf[ks] = *(const half8*)(Qg + (size_t)lid * HD + ks * 16 + hl * 8);

    f32x16 Oa[2] = {};    // D[q][d]: d = dt*32+lid, q = (reg&3)+8*(reg>>2)+4*hl
    float l2 = 0.f;       // per-lane partial denom for q = lid
    const half2v one2 = { (_Float16)1.0f, (_Float16)1.0f };

    // ---- stage tile 0 into buffer 0 (wave w issues rows 8w.. and 8(w+4)..)
    {
        _Float16* KL = (_Float16*)(pool);
        _Float16* VL = (_Float16*)(pool + 16384);
        #pragma unroll
        for (int jj = 0; jj < 2; ++jj) {
            const int j = w + jj * 4;
            const int row = 8 * j + srow;
            gload_lds16(Kg + (size_t)row * HD + schk * 8, KL + j * 512);
            gload_lds16(Vg + (size_t)row * SEQ + schk * 8, VL + j * 512);
        }
    }

    for (int it = 0; it < SEQ / 64; ++it) {
        __syncthreads();   // vmcnt(0)+barrier: tile `it` staged, prev compute done

        // ---- issue next-tile staging into the other buffer (overlaps compute)
        if (it < SEQ / 64 - 1) {
            const int kb = (it + 1) * 64;
            _Float16* KL = (_Float16*)(pool + ((it + 1) & 1) * 8192);
            _Float16* VL = (_Float16*)(pool + 16384 + ((it + 1) & 1) * 8192);
            #pragma unroll
            for (int jj = 0; jj < 2; ++jj) {
                const int j = w + jj * 4;
                const int row = 8 * j + srow;
                gload_lds16(Kg + (size_t)(kb + row) * HD + schk * 8, KL + j * 512);
                gload_lds16(Vg + (size_t)row * SEQ + kb + schk * 8, VL + j * 512);
            }
        }

        const _Float16* KL = (const _Float16*)(pool + (it & 1) * 8192);
        const _Float16* VL = (const _Float16*)(pool + 16384 + (it & 1) * 8192);

        // ---- K A-fragments: A[m=key][k=d], key = kt*32+lid, d = ks*16+hl*8+j
        half8 kf[2][4];
        #pragma unroll
        for (int kt = 0; kt < 2; ++kt)
            #pragma unroll
            for (int ks = 0; ks < 4; ++ks)
                kf[kt][ks] = *(const half8*)(KL + (kt * 32 + lid) * 64 +
                                             (((ks * 2 + hl) ^ (lid & 7)) * 8));

        // ---- S^T = K.Q^T : D[key][q]
        f32x16 sacc[2];
        __builtin_amdgcn_s_setprio(1);
        #pragma unroll
        for (int kt = 0; kt < 2; ++kt) {
            f32x16 s = {};
            #pragma unroll
            for (int ks = 0; ks < 4; ++ks)
                s = MFMA32(kf[kt][ks], Qf[ks], s);
            sacc[kt] = s;
        }
        __builtin_amdgcn_s_setprio(0);

        // ---- V B-fragments: B[k=key][n=d], key = kstep*16+hl*8+j, d = dt*32+lid
        half8 vf[4][2];
        #pragma unroll
        for (int kstep = 0; kstep < 4; ++kstep)
            #pragma unroll
            for (int dt = 0; dt < 2; ++dt)
                vf[kstep][dt] = *(const half8*)(VL + (dt * 32 + lid) * 64 +
                                                (((kstep * 2 + hl) ^ (lid & 7)) * 8));

        // ---- P = exp2(S); l += sum; pack pairs of consecutive keys to fp16
        unsigned cf[2][4][2];
        #pragma unroll
        for (int kt = 0; kt < 2; ++kt)
            #pragma unroll
            for (int g = 0; g < 4; ++g) {
                const float p0 = __builtin_amdgcn_exp2f(sacc[kt][g * 4 + 0]);
                const float p1 = __builtin_amdgcn_exp2f(sacc[kt][g * 4 + 1]);
                const float p2 = __builtin_amdgcn_exp2f(sacc[kt][g * 4 + 2]);
                const float p3 = __builtin_amdgcn_exp2f(sacc[kt][g * 4 + 3]);
                const unsigned ca = pack2u(p0, p1);
                const unsigned cb = pack2u(p2, p3);
                l2 = __builtin_amdgcn_fdot2(__builtin_bit_cast(half2v, ca), one2, l2, false);
                l2 = __builtin_amdgcn_fdot2(__builtin_bit_cast(half2v, cb), one2, l2, false);
                cf[kt][g][0] = ca;
                cf[kt][g][1] = cb;
            }

        // ---- PV with in-register transpose: per kstep build A-frag
        __builtin_amdgcn_s_setprio(1);
        #pragma unroll
        for (int kstep = 0; kstep < 4; ++kstep) {
            const int kt = kstep >> 1, g0 = (kstep & 1) * 2;
            const u32x2 r0 = __builtin_amdgcn_permlane32_swap(
                cf[kt][g0][0], cf[kt][g0 + 1][0], false, false);
            const u32x2 r1 = __builtin_amdgcn_permlane32_swap(
                cf[kt][g0][1], cf[kt][g0 + 1][1], false, false);
            const u32x4 pw = { r0[0], r1[0], r0[1], r1[1] };
            const half8 pa = __builtin_bit_cast(half8, pw);
            #pragma unroll
            for (int dt = 0; dt < 2; ++dt)
                Oa[dt] = MFMA32(pa, vf[kstep][dt], Oa[dt]);
        }
        __builtin_amdgcn_s_setprio(0);
    }

    // ---- deferred denominator: reduce over lane halves, publish
    l2 += __shfl_xor(l2, 32, 64);
    if (l < 32) lW[w * 32 + l] = l2;
    __syncthreads();   // all LDS reads done -> safe to alias pool as Obuf

    // ---- O (C-layout regs) -> Obuf [128][68] fp32
    float* Ob = (float*)pool;
    #pragma unroll
    for (int dt = 0; dt < 2; ++dt)
        #pragma unroll
        for (int g = 0; g < 4; ++g)
            #pragma unroll
            for (int r = 0; r < 4; ++r)
                Ob[(w * 32 + g * 8 + hl * 4 + r) * 68 + dt * 32 + lid] = Oa[dt][g * 4 + r];
    __syncthreads();

    // ---- normalize + store AO [token][1024] fp16 (16B stores)
    {
        const int row = t >> 1, cb = (t & 1) * 32;
        const float inv = 1.0f / lW[row];
        _Float16* dst = AO + ((size_t)b * SEQ + q0 + row) * DM + h * HD + cb;
        #pragma unroll
        for (int j = 0; j < 32; j += 8) {
            const f32x4 o0 = *(const f32x4*)(Ob + row * 68 + cb + j);
            const f32x4 o1 = *(const f32x4*)(Ob + row * 68 + cb + j + 4);
            half8 hv = { (_Float16)(o0[0] * inv), (_Float16)(o0[1] * inv),
                         (_Float16)(o0[2] * inv), (_Float16)(o0[3] * inv),
                         (_Float16)(o1[0] * inv), (_Float16)(o1[1] * inv),
                         (_Float16)(o1[2] * inv), (_Float16)(o1[3] * inv) };
            *(half8*)(dst + j) = hv;
        }
    }
}

// ---------------------------------------------------------------------------
extern "C" void kernel_launch(void* const* d_in, const int* in_sizes, int n_in,
                              void* d_out, int out_size, void* d_ws, size_t ws_size,
                              hipStream_t stream)
{
    const float* q  = (const float*)d_in[0];
    const float* k  = (const float*)d_in[1];
    const float* v  = (const float*)d_in[2];
    const float* Wq = (const float*)d_in[3];
    const float* bq = (const float*)d_in[4];
    const float* Wk = (const float*)d_in[5];
    const float* bk = (const float*)d_in[6];
    const float* Wv = (const float*)d_in[7];
    const float* bv = (const float*)d_in[8];
    const float* Wo = (const float*)d_in[9];
    const float* bo = (const float*)d_in[10];
    float* out = (float*)d_out;

    const size_t TD = (size_t)TOKENS * DM;     // 8.39M
    const size_t WD = (size_t)DM * DM;         // 1.05M
    _Float16* ws = (_Float16*)d_ws;
    _Float16* cvtbase = ws;                    // q16|k16|v16|wq16|wk16|wv16|wo16
    _Float16* q16  = ws;
    _Float16* wq16 = ws + 3 * TD;
    _Float16* wo16 = wq16 + 3 * WD;
    _Float16* Qw   = ws + 3 * TD + 4 * WD;     // Qw|Kw|Vtw contiguous
    _Float16* Kw   = Qw + TD;
    _Float16* Vtw  = Kw + TD;
    _Float16* AOw  = Vtw + TD;                 // also reused as natural-V scratch

    const int gC = (int)((3 * TD + 4 * WD) / 4 / 256);   // 28672
    cvt_all<<<gC, 256, 0, stream>>>(q, k, v, Wq, Wk, Wv, Wo, cvtbase);

    const float qscale = 0.18033688011112042f; // log2(e)/sqrt(64)
    qkv_gemm<<<dim3(TOKENS / 128, DM / 128, 3), 256, 0, stream>>>(
        q16, wq16, bq, bk, bv, Qw, /*Cv=*/AOw, qscale);

    vtr<<<dim3(SEQ / 64, BATCH * NH), 256, 0, stream>>>(AOw, Vtw);

    flash16<<<dim3((SEQ / 128) * BATCH * NH), 256, 0, stream>>>(Qw, Kw, Vtw, AOw);

    out_gemm<<<dim3(TOKENS / 128, DM / 128, 1), 256, 0, stream>>>(AOw, wo16, bo, out);
}

// Round 9
// 345.965 us; speedup vs baseline: 1.1070x; 1.0066x over previous
//
#include <hip/hip_runtime.h>
#include <math.h>

#define DM    1024
#define NH    16
#define HD    64
#define SEQ   2048
#define BATCH 4
#define TOKENS (BATCH * SEQ)     // 8192

typedef _Float16 half2v __attribute__((ext_vector_type(2)));
typedef __fp16   fp16x2 __attribute__((ext_vector_type(2)));
typedef _Float16 half4  __attribute__((ext_vector_type(4)));
typedef _Float16 half8  __attribute__((ext_vector_type(8)));
typedef float    f32x4  __attribute__((ext_vector_type(4)));
typedef float    f32x16 __attribute__((ext_vector_type(16)));
typedef unsigned int u32x2 __attribute__((ext_vector_type(2)));
typedef unsigned int u32x4 __attribute__((ext_vector_type(4)));

typedef const __attribute__((address_space(1))) void* gas_p;
typedef __attribute__((address_space(3))) void*       las_p;

__device__ __forceinline__ void gload_lds16(const void* g, void* l) {
    __builtin_amdgcn_global_load_lds((gas_p)g, (las_p)l, 16, 0, 0);
}

__device__ __forceinline__ unsigned pack2u(float a, float b) {
    fp16x2 r = __builtin_amdgcn_cvt_pkrtz(a, b);
    return __builtin_bit_cast(unsigned, r);
}

#define MFMA16(a, b, c) __builtin_amdgcn_mfma_f32_16x16x32_f16((a), (b), (c), 0, 0, 0)
#define MFMA32(a, b, c) __builtin_amdgcn_mfma_f32_32x32x16_f16((a), (b), (c), 0, 0, 0)

// ---------------------------------------------------------------------------
// One fused fp32->fp16 convert over all 7 tensors (dst regions contiguous).
// ---------------------------------------------------------------------------
__global__ __launch_bounds__(256) void cvt_all(
    const float* __restrict__ q, const float* __restrict__ k,
    const float* __restrict__ v, const float* __restrict__ wq,
    const float* __restrict__ wk, const float* __restrict__ wv,
    const float* __restrict__ wo, _Float16* __restrict__ dst)
{
    const size_t TD = (size_t)TOKENS * DM, WD = (size_t)DM * DM;
    const size_t i = ((size_t)blockIdx.x * 256 + threadIdx.x) * 4;
    const float* s; size_t off;
    if      (i <     TD)          { s = q;  off = i; }
    else if (i < 2 * TD)          { s = k;  off = i - TD; }
    else if (i < 3 * TD)          { s = v;  off = i - 2 * TD; }
    else if (i < 3 * TD + WD)     { s = wq; off = i - 3 * TD; }
    else if (i < 3 * TD + 2 * WD) { s = wk; off = i - 3 * TD - WD; }
    else if (i < 3 * TD + 3 * WD) { s = wv; off = i - 3 * TD - 2 * WD; }
    else                          { s = wo; off = i - 3 * TD - 3 * WD; }
    const float4 x = *(const float4*)(s + off);
    half4 h = { (_Float16)x.x, (_Float16)x.y, (_Float16)x.z, (_Float16)x.w };
    *(half4*)(dst + i) = h;
}

// ---------------------------------------------------------------------------
// Fused QKV projection: grid (64, 8, 3); z selects A/W/bias/C and store mode.
// z 0,1: per-head [B,H,S,hd] fp16 (z0 scaled by log2(e)/8); z 2: [B,H,hd,S].
// v10: double-buffered staging (1 barrier/iter, loads span compute) +
// chunk^row&3 swizzle on stage-src and frag-read (8-way -> 4-way conflicts).
// ---------------------------------------------------------------------------
__global__ __launch_bounds__(256) void qkv_gemm(
    const _Float16* __restrict__ Abase, const _Float16* __restrict__ Wbase,
    const float* __restrict__ bq, const float* __restrict__ bk,
    const float* __restrict__ bv, _Float16* __restrict__ Cbase, float qscale)
{
    __shared__ __align__(16) _Float16 As[2][128 * 32];
    __shared__ __align__(16) _Float16 Ws[2][128 * 32];

    const int z = blockIdx.z;
    const size_t TD = (size_t)TOKENS * DM, WD = (size_t)DM * DM;
    const _Float16* A = Abase + (size_t)z * TD;
    const _Float16* W = Wbase + (size_t)z * WD;
    const float* bias = (z == 0) ? bq : (z == 1) ? bk : bv;
    _Float16* C = Cbase + (size_t)z * TD;
    const float scale = (z == 0) ? qscale : 1.0f;

    const int t = threadIdx.x;
    const int w = t >> 6, l = t & 63;
    const int tx = l & 15, quad = l >> 4;
    const int m0 = blockIdx.x * 128, n0 = blockIdx.y * 128;
    const int wm = (w & 1) * 64, wn = (w >> 1) * 64;
    const int srow = t >> 2;
    const int schk = (t & 3) ^ (srow & 3);   // swizzled 8-half chunk in 64B row

    const _Float16* Ag = A + (size_t)m0 * DM;
    const _Float16* Wg = W + (size_t)n0 * DM;

    f32x4 acc[4][4] = {};

    // prologue: stage k0=0 into buffer 0
    #pragma unroll
    for (int i = 0; i < 2; ++i) {
        gload_lds16(Ag + (size_t)(i * 64 + srow) * DM + schk * 8,
                    As[0] + (size_t)(i * 256 + (t & ~63)) * 8);
        gload_lds16(Wg + (size_t)(i * 64 + srow) * DM + schk * 8,
                    Ws[0] + (size_t)(i * 256 + (t & ~63)) * 8);
    }

    for (int k0 = 0; k0 < DM; k0 += 32) {
        __syncthreads();   // vmcnt(0)+barrier: buffer cur is staged
        const int cur = (k0 >> 5) & 1;
        if (k0 + 32 < DM) {
            #pragma unroll
            for (int i = 0; i < 2; ++i) {
                gload_lds16(Ag + (size_t)(i * 64 + srow) * DM + k0 + 32 + schk * 8,
                            As[cur ^ 1] + (size_t)(i * 256 + (t & ~63)) * 8);
                gload_lds16(Wg + (size_t)(i * 64 + srow) * DM + k0 + 32 + schk * 8,
                            Ws[cur ^ 1] + (size_t)(i * 256 + (t & ~63)) * 8);
            }
        }

        half8 af[4], bf[4];
        #pragma unroll
        for (int mt = 0; mt < 4; ++mt) {
            const int r = wm + mt * 16 + tx;
            af[mt] = *(const half8*)(As[cur] + r * 32 + ((quad ^ (r & 3)) * 8));
        }
        #pragma unroll
        for (int nt = 0; nt < 4; ++nt) {
            const int r = wn + nt * 16 + tx;
            bf[nt] = *(const half8*)(Ws[cur] + r * 32 + ((quad ^ (r & 3)) * 8));
        }
        #pragma unroll
        for (int mt = 0; mt < 4; ++mt)
            #pragma unroll
            for (int nt = 0; nt < 4; ++nt)
                acc[mt][nt] = MFMA16(af[mt], bf[nt], acc[mt][nt]);
    }

    float bsv[4];
    #pragma unroll
    for (int nt = 0; nt < 4; ++nt) bsv[nt] = bias[n0 + wn + nt * 16 + tx];

    #pragma unroll
    for (int mt = 0; mt < 4; ++mt) {
        #pragma unroll
        for (int nt = 0; nt < 4; ++nt) {
            const int n = n0 + wn + nt * 16 + tx;
            const int mr0 = m0 + wm + mt * 16 + quad * 4;
            const int h = n >> 6, d = n & 63;
            if (z < 2) {
                #pragma unroll
                for (int r = 0; r < 4; ++r) {
                    const int m = mr0 + r;
                    const int b = m >> 11, s = m & (SEQ - 1);
                    const float vv = (acc[mt][nt][r] + bsv[nt]) * scale;
                    C[(((size_t)b * NH + h) * SEQ + s) * HD + d] = (_Float16)vv;
                }
            } else {
                const int b = mr0 >> 11, s0 = mr0 & (SEQ - 1);
                half4 hv = { (_Float16)(acc[mt][nt][0] + bsv[nt]),
                             (_Float16)(acc[mt][nt][1] + bsv[nt]),
                             (_Float16)(acc[mt][nt][2] + bsv[nt]),
                             (_Float16)(acc[mt][nt][3] + bsv[nt]) };
                *(half4*)(C + (((size_t)b * NH + h) * HD + d) * SEQ + s0) = hv;
            }
        }
    }
}

// ---------------------------------------------------------------------------
// Output projection GEMM: C fp32 [m,n] = A[m,k] W[n,k] + bias.
// v10: same double-buffer + swizzle as qkv_gemm.
// ---------------------------------------------------------------------------
__global__ __launch_bounds__(256) void out_gemm(
    const _Float16* __restrict__ A, const _Float16* __restrict__ W,
    const float* __restrict__ bias, float* __restrict__ C)
{
    __shared__ __align__(16) _Float16 As[2][128 * 32];
    __shared__ __align__(16) _Float16 Ws[2][128 * 32];

    const int t = threadIdx.x;
    const int w = t >> 6, l = t & 63;
    const int tx = l & 15, quad = l >> 4;
    const int m0 = blockIdx.x * 128, n0 = blockIdx.y * 128;
    const int wm = (w & 1) * 64, wn = (w >> 1) * 64;
    const int srow = t >> 2;
    const int schk = (t & 3) ^ (srow & 3);

    const _Float16* Ag = A + (size_t)m0 * DM;
    const _Float16* Wg = W + (size_t)n0 * DM;

    f32x4 acc[4][4] = {};

    #pragma unroll
    for (int i = 0; i < 2; ++i) {
        gload_lds16(Ag + (size_t)(i * 64 + srow) * DM + schk * 8,
                    As[0] + (size_t)(i * 256 + (t & ~63)) * 8);
        gload_lds16(Wg + (size_t)(i * 64 + srow) * DM + schk * 8,
                    Ws[0] + (size_t)(i * 256 + (t & ~63)) * 8);
    }

    for (int k0 = 0; k0 < DM; k0 += 32) {
        __syncthreads();
        const int cur = (k0 >> 5) & 1;
        if (k0 + 32 < DM) {
            #pragma unroll
            for (int i = 0; i < 2; ++i) {
                gload_lds16(Ag + (size_t)(i * 64 + srow) * DM + k0 + 32 + schk * 8,
                            As[cur ^ 1] + (size_t)(i * 256 + (t & ~63)) * 8);
                gload_lds16(Wg + (size_t)(i * 64 + srow) * DM + k0 + 32 + schk * 8,
                            Ws[cur ^ 1] + (size_t)(i * 256 + (t & ~63)) * 8);
            }
        }

        half8 af[4], bf[4];
        #pragma unroll
        for (int mt = 0; mt < 4; ++mt) {
            const int r = wm + mt * 16 + tx;
            af[mt] = *(const half8*)(As[cur] + r * 32 + ((quad ^ (r & 3)) * 8));
        }
        #pragma unroll
        for (int nt = 0; nt < 4; ++nt) {
            const int r = wn + nt * 16 + tx;
            bf[nt] = *(const half8*)(Ws[cur] + r * 32 + ((quad ^ (r & 3)) * 8));
        }
        #pragma unroll
        for (int mt = 0; mt < 4; ++mt)
            #pragma unroll
            for (int nt = 0; nt < 4; ++nt)
                acc[mt][nt] = MFMA16(af[mt], bf[nt], acc[mt][nt]);
    }

    float bsv[4];
    #pragma unroll
    for (int nt = 0; nt < 4; ++nt) bsv[nt] = bias[n0 + wn + nt * 16 + tx];

    #pragma unroll
    for (int mt = 0; mt < 4; ++mt)
        #pragma unroll
        for (int nt = 0; nt < 4; ++nt) {
            const int n = n0 + wn + nt * 16 + tx;
            const int mr0 = m0 + wm + mt * 16 + quad * 4;
            #pragma unroll
            for (int r = 0; r < 4; ++r)
                C[(size_t)(mr0 + r) * DM + n] = acc[mt][nt][r] + bsv[nt];
        }
}

// ---------------------------------------------------------------------------
// Flash attention v4 (best measured: 95.2 us) — 32x32 MFMA + in-register
// softmax. grid 1024 (XCD-bijective decode), block 256 = 4 waves; wave w
// owns q rows w*32..w*32+31 (split-Q, l deferred). K-tile 64 keys,
// double-buffered LDS via global_load_lds with XOR-swizzled global source;
// fragment reads apply the same involution -> conflict-free b128.
// ---------------------------------------------------------------------------
__global__ __launch_bounds__(256, 3) void flash16(
    const _Float16* __restrict__ Q, const _Float16* __restrict__ K,
    const _Float16* __restrict__ Vt, _Float16* __restrict__ AO)
{
    // pool: Kst[2][8KB] | Vst[2][8KB] = 32768 B
    // epilogue aliases pool as float Obuf[128][68] (34816 B)
    __shared__ __align__(16) char pool[34816];
    __shared__ float lW[128];

    const int t = threadIdx.x, w = t >> 6, l = t & 63;
    const int lid = l & 31, hl = l >> 5;

    // XCD-bijective block swizzle: all 16 q-tiles of one (b,h) on one XCD.
    const int bid = blockIdx.x;
    const int xcd = bid & 7, loc = bid >> 3;
    const int bh = xcd * 8 + (loc >> 4);
    const int q0 = (loc & 15) * 128;
    const int b = bh >> 4, h = bh & 15;

    const _Float16* Qg = Q + ((size_t)bh * SEQ + q0 + w * 32) * HD;
    const _Float16* Kg = K + (size_t)bh * SEQ * HD;
    const _Float16* Vg = Vt + (size_t)bh * HD * SEQ;

    // staging source swizzle (per lane, constant across iters)
    const int srow = l >> 3;             // 0..7 row within 8-row instr group
    const int schk = (l & 7) ^ srow;     // swizzled 16B chunk within 128B row

    // Q B-fragments, in registers whole kernel: B[k=d][n=q], k = hl*8+j
    half8 Qf[4];
    #pragma unroll
    for (int ks = 0; ks < 4; ++ks)
        Qf[ks] = *(const half8*)(Qg + (size_t)lid * HD + ks * 16 + hl * 8);

    f32x16 Oa[2] = {};    // D[q][d]: d = dt*32+lid, q = (reg&3)+8*(reg>>2)+4*hl
    float l2 = 0.f;       // per-lane partial denom for q = lid
    const half2v one2 = { (_Float16)1.0f, (_Float16)1.0f };

    // ---- stage tile 0 into buffer 0 (wave w issues rows 8w.. and 8(w+4)..)
    {
        _Float16* KL = (_Float16*)(pool);
        _Float16* VL = (_Float16*)(pool + 16384);
        #pragma unroll
        for (int jj = 0; jj < 2; ++jj) {
            const int j = w + jj * 4;
            const int row = 8 * j + srow;
            gload_lds16(Kg + (size_t)row * HD + schk * 8, KL + j * 512);
            gload_lds16(Vg + (size_t)row * SEQ + schk * 8, VL + j * 512);
        }
    }

    for (int it = 0; it < SEQ / 64; ++it) {
        __syncthreads();   // vmcnt(0)+barrier: tile `it` staged, prev compute done

        // ---- issue next-tile staging into the other buffer (overlaps compute)
        if (it < SEQ / 64 - 1) {
            const int kb = (it + 1) * 64;
            _Float16* KL = (_Float16*)(pool + ((it + 1) & 1) * 8192);
            _Float16* VL = (_Float16*)(pool + 16384 + ((it + 1) & 1) * 8192);
            #pragma unroll
            for (int jj = 0; jj < 2; ++jj) {
                const int j = w + jj * 4;
                const int row = 8 * j + srow;
                gload_lds16(Kg + (size_t)(kb + row) * HD + schk * 8, KL + j * 512);
                gload_lds16(Vg + (size_t)row * SEQ + kb + schk * 8, VL + j * 512);
            }
        }

        const _Float16* KL = (const _Float16*)(pool + (it & 1) * 8192);
        const _Float16* VL = (const _Float16*)(pool + 16384 + (it & 1) * 8192);

        // ---- K A-fragments: A[m=key][k=d], key = kt*32+lid, d = ks*16+hl*8+j
        half8 kf[2][4];
        #pragma unroll
        for (int kt = 0; kt < 2; ++kt)
            #pragma unroll
            for (int ks = 0; ks < 4; ++ks)
                kf[kt][ks] = *(const half8*)(KL + (kt * 32 + lid) * 64 +
                                             (((ks * 2 + hl) ^ (lid & 7)) * 8));

        // ---- S^T = K.Q^T : D[key][q]
        f32x16 sacc[2];
        __builtin_amdgcn_s_setprio(1);
        #pragma unroll
        for (int kt = 0; kt < 2; ++kt) {
            f32x16 s = {};
            #pragma unroll
            for (int ks = 0; ks < 4; ++ks)
                s = MFMA32(kf[kt][ks], Qf[ks], s);
            sacc[kt] = s;
        }
        __builtin_amdgcn_s_setprio(0);

        // ---- V B-fragments: B[k=key][n=d], key = kstep*16+hl*8+j, d = dt*32+lid
        half8 vf[4][2];
        #pragma unroll
        for (int kstep = 0; kstep < 4; ++kstep)
            #pragma unroll
            for (int dt = 0; dt < 2; ++dt)
                vf[kstep][dt] = *(const half8*)(VL + (dt * 32 + lid) * 64 +
                                                (((kstep * 2 + hl) ^ (lid & 7)) * 8));

        // ---- P = exp2(S); l += sum; pack pairs of consecutive keys to fp16
        unsigned cf[2][4][2];
        #pragma unroll
        for (int kt = 0; kt < 2; ++kt)
            #pragma unroll
            for (int g = 0; g < 4; ++g) {
                const float p0 = __builtin_amdgcn_exp2f(sacc[kt][g * 4 + 0]);
                const float p1 = __builtin_amdgcn_exp2f(sacc[kt][g * 4 + 1]);
                const float p2 = __builtin_amdgcn_exp2f(sacc[kt][g * 4 + 2]);
                const float p3 = __builtin_amdgcn_exp2f(sacc[kt][g * 4 + 3]);
                const unsigned ca = pack2u(p0, p1);
                const unsigned cb = pack2u(p2, p3);
                l2 = __builtin_amdgcn_fdot2(__builtin_bit_cast(half2v, ca), one2, l2, false);
                l2 = __builtin_amdgcn_fdot2(__builtin_bit_cast(half2v, cb), one2, l2, false);
                cf[kt][g][0] = ca;
                cf[kt][g][1] = cb;
            }

        // ---- PV with in-register transpose: per kstep build A-frag
        __builtin_amdgcn_s_setprio(1);
        #pragma unroll
        for (int kstep = 0; kstep < 4; ++kstep) {
            const int kt = kstep >> 1, g0 = (kstep & 1) * 2;
            const u32x2 r0 = __builtin_amdgcn_permlane32_swap(
                cf[kt][g0][0], cf[kt][g0 + 1][0], false, false);
            const u32x2 r1 = __builtin_amdgcn_permlane32_swap(
                cf[kt][g0][1], cf[kt][g0 + 1][1], false, false);
            const u32x4 pw = { r0[0], r1[0], r0[1], r1[1] };
            const half8 pa = __builtin_bit_cast(half8, pw);
            #pragma unroll
            for (int dt = 0; dt < 2; ++dt)
                Oa[dt] = MFMA32(pa, vf[kstep][dt], Oa[dt]);
        }
        __builtin_amdgcn_s_setprio(0);
    }

    // ---- deferred denominator: reduce over lane halves, publish
    l2 += __shfl_xor(l2, 32, 64);
    if (l < 32) lW[w * 32 + l] = l2;
    __syncthreads();   // all LDS reads done -> safe to alias pool as Obuf

    // ---- O (C-layout regs) -> Obuf [128][68] fp32
    float* Ob = (float*)pool;
    #pragma unroll
    for (int dt = 0; dt < 2; ++dt)
        #pragma unroll
        for (int g = 0; g < 4; ++g)
            #pragma unroll
            for (int r = 0; r < 4; ++r)
                Ob[(w * 32 + g * 8 + hl * 4 + r) * 68 + dt * 32 + lid] = Oa[dt][g * 4 + r];
    __syncthreads();

    // ---- normalize + store AO [token][1024] fp16 (16B stores)
    {
        const int row = t >> 1, cb = (t & 1) * 32;
        const float inv = 1.0f / lW[row];
        _Float16* dst = AO + ((size_t)b * SEQ + q0 + row) * DM + h * HD + cb;
        #pragma unroll
        for (int j = 0; j < 32; j += 8) {
            const f32x4 o0 = *(const f32x4*)(Ob + row * 68 + cb + j);
            const f32x4 o1 = *(const f32x4*)(Ob + row * 68 + cb + j + 4);
            half8 hv = { (_Float16)(o0[0] * inv), (_Float16)(o0[1] * inv),
                         (_Float16)(o0[2] * inv), (_Float16)(o0[3] * inv),
                         (_Float16)(o1[0] * inv), (_Float16)(o1[1] * inv),
                         (_Float16)(o1[2] * inv), (_Float16)(o1[3] * inv) };
            *(half8*)(dst + j) = hv;
        }
    }
}

// ---------------------------------------------------------------------------
extern "C" void kernel_launch(void* const* d_in, const int* in_sizes, int n_in,
                              void* d_out, int out_size, void* d_ws, size_t ws_size,
                              hipStream_t stream)
{
    const float* q  = (const float*)d_in[0];
    const float* k  = (const float*)d_in[1];
    const float* v  = (const float*)d_in[2];
    const float* Wq = (const float*)d_in[3];
    const float* bq = (const float*)d_in[4];
    const float* Wk = (const float*)d_in[5];
    const float* bk = (const float*)d_in[6];
    const float* Wv = (const float*)d_in[7];
    const float* bv = (const float*)d_in[8];
    const float* Wo = (const float*)d_in[9];
    const float* bo = (const float*)d_in[10];
    float* out = (float*)d_out;

    const size_t TD = (size_t)TOKENS * DM;     // 8.39M
    const size_t WD = (size_t)DM * DM;         // 1.05M
    _Float16* ws = (_Float16*)d_ws;
    _Float16* cvtbase = ws;                    // q16|k16|v16|wq16|wk16|wv16|wo16
    _Float16* q16  = ws;
    _Float16* wq16 = ws + 3 * TD;
    _Float16* wo16 = wq16 + 3 * WD;
    _Float16* Qw   = ws + 3 * TD + 4 * WD;     // Qw|Kw|Vtw contiguous
    _Float16* Kw   = Qw + TD;
    _Float16* Vtw  = Kw + TD;
    _Float16* AOw  = Vtw + TD;

    const int gC = (int)((3 * TD + 4 * WD) / 4 / 256);   // 28672
    cvt_all<<<gC, 256, 0, stream>>>(q, k, v, Wq, Wk, Wv, Wo, cvtbase);

    const float qscale = 0.18033688011112042f; // log2(e)/sqrt(64)
    qkv_gemm<<<dim3(TOKENS / 128, DM / 128, 3), 256, 0, stream>>>(
        q16, wq16, bq, bk, bv, Qw, qscale);

    flash16<<<dim3((SEQ / 128) * BATCH * NH), 256, 0, stream>>>(Qw, Kw, Vtw, AOw);

    out_gemm<<<dim3(TOKENS / 128, DM / 128, 1), 256, 0, stream>>>(AOw, wo16, bo, out);
}